// Round 12
// baseline (17878.149 us; speedup 1.0000x reference)
//
#include <hip/hip_runtime.h>
#include <math.h>

#define Bb 8
#define Tt 168
#define Nn 512
#define Cc 32
#define Ll 4
#define Kk 50
#define NCH 4
#define BPC 2                     // batches per chunk (chunk boundary = t==0, no cross-chunk reads)
#define BTc (BPC*Tt)              // 336
#define BTNc ((size_t)BTc*Nn)
#define BTCNc ((size_t)BTc*Cc*Nn)
#define BT (Bb*Tt)
#define BTN ((size_t)Bb*Tt*Nn)
#define BTCN ((size_t)Bb*Tt*Cc*Nn)
#define GRUB 64                   // GRU blocks: each owns 8 output cols, all batches
#define PUBW 32                   // words per (b,sl) publication slot (128B line)

typedef __attribute__((ext_vector_type(8))) short short8v;
typedef __attribute__((ext_vector_type(4))) float f32x4;
typedef __attribute__((ext_vector_type(2))) float f32x2;

__device__ __forceinline__ float sigm(float v) { return 1.0f/(1.0f + expf(-v)); }

__device__ __forceinline__ unsigned int f2bf(float x) {   // RNE, returns bits in low 16
  unsigned int u = __float_as_uint(x);
  u = u + 0x7FFFu + ((u >> 16) & 1u);
  return u >> 16;
}
__device__ __forceinline__ float bf2f(unsigned int h) {
  return __uint_as_float(h << 16);
}

// cache-bypassing vector store (coherence-point data plane)
__device__ __forceinline__ void byp_store4(float* p, f32x4 v) {
  asm volatile("global_store_dwordx4 %0, %1, off sc0 sc1" :: "v"(p), "v"(v) : "memory");
}

// publish 16 floats with tag embedded in every 16B unit (single-dwordx4 atomicity)
__device__ __forceinline__ void publish16(float* base, const float* v, int tag) {
  float ft = __uint_as_float((unsigned)tag);
  f32x4 u0 = {v[0],v[1],v[2],ft};
  f32x4 u1 = {v[3],v[4],v[5],ft};
  f32x4 u2 = {v[6],v[7],v[8],ft};
  f32x4 u3 = {v[9],v[10],v[11],ft};
  f32x4 u4 = {v[12],v[13],v[14],ft};
  f32x4 u5 = {v[15],0.f,0.f,ft};
  byp_store4(base,    u0); byp_store4(base+4,  u1); byp_store4(base+8,  u2);
  byp_store4(base+12, u3); byp_store4(base+16, u4); byp_store4(base+20, u5);
}

// ---------------- pack GRU weights block-sliced: wpack[sl][c][kk], kk over [z|r|hx|hh] ----------------
__global__ void k_wt2(const float* __restrict__ zl, const float* __restrict__ rl,
                      const float* __restrict__ hl, float* __restrict__ wpack) {
  int idx = blockIdx.x*256 + threadIdx.x;       // 64*8*3072 = 1572864
  if (idx >= GRUB*8*3072) return;
  int kk = idx % 3072;
  int c  = (idx / 3072) & 7;
  int sl = idx / (3072*8);
  int ncol = sl*8 + c;
  float v;
  if (kk < 1024)      v = zl[ncol*1024 + kk];
  else if (kk < 2048) v = rl[ncol*1024 + (kk-1024)];
  else if (kk < 2560) v = hl[ncol*1024 + (kk-2048)];
  else                v = hl[ncol*1024 + 512 + (kk-2560)];
  wpack[idx] = v;
}

// ---------------- adaptive adjacency: softmax(relu(nv1@nv2), axis=1) ----------------
__global__ void k_adp(const float* __restrict__ nv1, const float* __restrict__ nv2,
                      float* __restrict__ adp) {
  int i = blockIdx.x;
  __shared__ float row[512];
  __shared__ float red[256];
  float v1[10];
  #pragma unroll
  for (int k=0;k<10;k++) v1[k] = nv1[i*10+k];
  for (int jj = threadIdx.x; jj < 512; jj += 256) {
    float s = 0.f;
    #pragma unroll
    for (int k=0;k<10;k++) s += v1[k]*nv2[k*Nn + jj];
    row[jj] = fmaxf(s, 0.f);
  }
  __syncthreads();
  float m = fmaxf(row[threadIdx.x], row[threadIdx.x+256]);
  red[threadIdx.x] = m; __syncthreads();
  for (int s=128; s>0; s>>=1) { if (threadIdx.x < s) red[threadIdx.x] = fmaxf(red[threadIdx.x], red[threadIdx.x+s]); __syncthreads(); }
  float mx = red[0]; __syncthreads();
  float e0 = expf(row[threadIdx.x]      - mx);
  float e1 = expf(row[threadIdx.x+256]  - mx);
  red[threadIdx.x] = e0 + e1; __syncthreads();
  for (int s=128; s>0; s>>=1) { if (threadIdx.x < s) red[threadIdx.x] += red[threadIdx.x+s]; __syncthreads(); }
  float inv = 1.f/red[0];
  adp[(size_t)i*Nn + threadIdx.x]       = e0*inv;
  adp[(size_t)i*Nn + threadIdx.x + 256] = e1*inv;
}

// ---------------- split supports to transposed bf16 hi/lo: ShiT[s][n][k] ----------------
__global__ void k_sprep(const float* __restrict__ sup0, const float* __restrict__ sup1,
                        const float* __restrict__ adp,
                        unsigned short* __restrict__ ShiT, unsigned short* __restrict__ SloT) {
  int idx = blockIdx.x*256 + threadIdx.x;
  if (idx >= 3*512*512) return;
  int s = idx >> 18;
  int rem = idx & 262143;
  int n = rem >> 9, k = rem & 511;
  const float* S = (s==0) ? sup0 : (s==1) ? sup1 : adp;
  float v = S[k*512 + n];
  unsigned int h = f2bf(v);
  float lo = v - bf2f(h);
  ShiT[idx] = (unsigned short)h;
  SloT[idx] = (unsigned short)f2bf(lo);
}

// ---------------- input transform: x = conv1x1(input[[0,3,5,6]]) -> (B,T,C,N) ----------------
__global__ void k_intransform(const float* __restrict__ input, const float* __restrict__ skw,
                              const float* __restrict__ skb, float* __restrict__ x) {
  size_t idx = (size_t)blockIdx.x*256 + threadIdx.x;
  if (idx >= BTN) return;
  int n = idx & 511;
  size_t bt = idx >> 9;
  int b = (int)(bt / Tt), t = (int)(bt % Tt);
  size_t chs = (size_t)Tt*Nn;
  size_t base = (((size_t)b*7)*Tt + t)*Nn + n;
  float v0 = input[base + 0*chs];
  float v3 = input[base + 3*chs];
  float v5 = input[base + 5*chs];
  float v6 = input[base + 6*chs];
  float* xp = x + bt*Cc*Nn + n;
  #pragma unroll
  for (int c=0;c<32;c++)
    xp[(size_t)c*Nn] = skb[c] + skw[c*4+0]*v0 + skw[c*4+1]*v3 + skw[c*4+2]*v5 + skw[c*4+3]*v6;
}

// ---------------- fused filter/gate conv1x2 -> xg_q ; gout_q = W0@xg + bias (chunk-local) ----------------
__launch_bounds__(256)
__global__ void k_fgconv(const float* __restrict__ x, const float* __restrict__ fw,
                         const float* __restrict__ fb, const float* __restrict__ gw,
                         const float* __restrict__ gb, const float* __restrict__ gcwl,
                         const float* __restrict__ gcb,
                         float* __restrict__ xg, float* __restrict__ gout, int chunk) {
  __shared__ float sfw[2048], sgw[2048], sw0[1024], sfb[32], sgb[32], sgcb[32];
  for (int l = threadIdx.x; l < 2048; l += 256) { sfw[l] = fw[l]; sgw[l] = gw[l]; }
  for (int l = threadIdx.x; l < 1024; l += 256) sw0[l] = gcwl[(l>>5)*224 + (l&31)];
  if (threadIdx.x < 32) {
    sfb[threadIdx.x] = fb[threadIdx.x];
    sgb[threadIdx.x] = gb[threadIdx.x];
    sgcb[threadIdx.x] = gcb[threadIdx.x];
  }
  __syncthreads();
  size_t idx = (size_t)blockIdx.x*256 + threadIdx.x;
  if (idx >= BTNc) return;
  int n = idx & 511;
  size_t btl = idx >> 9;
  int t = (int)(btl % Tt);
  size_t btg = (size_t)chunk*BTc + btl;
  const float* xp = x + btg*Cc*Nn + n;
  float xl[32], xr[32];
  #pragma unroll
  for (int c=0;c<32;c++) xr[c] = xp[(size_t)c*Nn];
  if (t == 0) {
    #pragma unroll
    for (int c=0;c<32;c++) xl[c] = 0.f;
  } else {
    const float* xq = xp - (size_t)Cc*Nn;
    #pragma unroll
    for (int c=0;c<32;c++) xl[c] = xq[(size_t)c*Nn];
  }
  float xgv[32];
  for (int c=0;c<32;c++) {
    float f = sfb[c], g = sgb[c];
    #pragma unroll
    for (int cp=0;cp<32;cp++) {
      f += xl[cp]*sfw[(c*32+cp)*2] + xr[cp]*sfw[(c*32+cp)*2+1];
      g += xl[cp]*sgw[(c*32+cp)*2] + xr[cp]*sgw[(c*32+cp)*2+1];
    }
    xgv[c] = tanhf(f) * sigm(g);
  }
  float* xgp = xg + btl*Cc*Nn + n;
  #pragma unroll
  for (int c=0;c<32;c++) xgp[(size_t)c*Nn] = xgv[c];
  float* gp = gout + btl*Cc*Nn + n;
  for (int o=0;o<32;o++) {
    float s = sgcb[o];
    #pragma unroll
    for (int c=0;c<32;c++) s += sw0[o*32+c]*xgv[c];
    gp[(size_t)o*Nn] = s;
  }
}

// ---------------- support GEMM via split-bf16 MFMA (round-10 proven version) ----------------
__launch_bounds__(256)
__global__ void k_supmfma(const float* __restrict__ X,
                          const unsigned short* __restrict__ ShiT,
                          const unsigned short* __restrict__ SloT,
                          const float* __restrict__ gcw, int pslot,
                          float* __restrict__ Y, float* __restrict__ gout, int storeY) {
  __shared__ unsigned char smem[64*132*4];      // pool: staging (30720B) then sY (33792B)
  __shared__ float sW[1024];
  unsigned short* sXhi = (unsigned short*)smem;                 // 64*40
  unsigned short* sXlo = sXhi + 2560;
  unsigned short* sShi = sXlo + 2560;                           // 128*40
  unsigned short* sSlo = sShi + 5120;
  float* sY = (float*)smem;                                     // 64*132 (after K loop)
#define MW 40

  const int tid  = threadIdx.x;
  const int bt2  = blockIdx.x >> 2;
  const int colg = blockIdx.x & 3;
  const int bt0  = bt2*2;
  const int n0   = colg*128;
  const int lane = tid & 63, wv = tid >> 6;
  const int kb   = (lane >> 4)*8;

  for (int l = tid; l < 1024; l += 256)
    sW[l] = gcw[(l>>5)*224 + pslot*32 + (l&31)];

  f32x4 acc[4][2];
  #pragma unroll
  for (int i=0;i<4;i++) {
    #pragma unroll
    for (int j=0;j<2;j++) { acc[i][j].x=0.f; acc[i][j].y=0.f; acc[i][j].z=0.f; acc[i][j].w=0.f; }
  }

  const int sm  = tid >> 2;              // X stage: row 0..63
  const int skp = (tid & 3)*8;           // k part
  const size_t xrow = ((size_t)(bt0 + (sm>>5))*Cc + (sm&31))*Nn;
  const int sn  = tid >> 1;              // S stage: col-row 0..127
  const int shp = (tid & 1)*16;          // 16-k half

  for (int kc = 0; kc < 16; kc++) {
    const int k0 = kc*32;
    {
      float4 a0 = *reinterpret_cast<const float4*>(&X[xrow + k0 + skp]);
      float4 a1 = *reinterpret_cast<const float4*>(&X[xrow + k0 + skp + 4]);
      float v[8] = {a0.x,a0.y,a0.z,a0.w,a1.x,a1.y,a1.z,a1.w};
      unsigned int h[8], l[8];
      #pragma unroll
      for (int i=0;i<8;i++) {
        h[i] = f2bf(v[i]);
        l[i] = f2bf(v[i] - bf2f(h[i]));
      }
      uint4 H = { h[0]|(h[1]<<16), h[2]|(h[3]<<16), h[4]|(h[5]<<16), h[6]|(h[7]<<16) };
      uint4 L = { l[0]|(l[1]<<16), l[2]|(l[3]<<16), l[4]|(l[5]<<16), l[6]|(l[7]<<16) };
      *reinterpret_cast<uint4*>(&sXhi[sm*MW + skp]) = H;
      *reinterpret_cast<uint4*>(&sXlo[sm*MW + skp]) = L;
    }
    {
      const size_t srow = (size_t)(n0 + sn)*512 + k0 + shp;
      *reinterpret_cast<uint4*>(&sShi[sn*MW + shp])     = *reinterpret_cast<const uint4*>(&ShiT[srow]);
      *reinterpret_cast<uint4*>(&sShi[sn*MW + shp + 8]) = *reinterpret_cast<const uint4*>(&ShiT[srow + 8]);
      *reinterpret_cast<uint4*>(&sSlo[sn*MW + shp])     = *reinterpret_cast<const uint4*>(&SloT[srow]);
      *reinterpret_cast<uint4*>(&sSlo[sn*MW + shp + 8]) = *reinterpret_cast<const uint4*>(&SloT[srow + 8]);
    }
    __syncthreads();
    short8v bhi[2], blo[2];
    #pragma unroll
    for (int ct=0; ct<2; ct++) {
      int col = wv*32 + ct*16 + (lane & 15);
      bhi[ct] = *reinterpret_cast<const short8v*>(&sShi[col*MW + kb]);
      blo[ct] = *reinterpret_cast<const short8v*>(&sSlo[col*MW + kb]);
    }
    #pragma unroll
    for (int rt=0; rt<4; rt++) {
      int row = rt*16 + (lane & 15);
      short8v ahi = *reinterpret_cast<const short8v*>(&sXhi[row*MW + kb]);
      short8v alo = *reinterpret_cast<const short8v*>(&sXlo[row*MW + kb]);
      #pragma unroll
      for (int ct=0; ct<2; ct++) {
        acc[rt][ct] = __builtin_amdgcn_mfma_f32_16x16x32_bf16(ahi, bhi[ct], acc[rt][ct], 0, 0, 0);
        acc[rt][ct] = __builtin_amdgcn_mfma_f32_16x16x32_bf16(ahi, blo[ct], acc[rt][ct], 0, 0, 0);
        acc[rt][ct] = __builtin_amdgcn_mfma_f32_16x16x32_bf16(alo, bhi[ct], acc[rt][ct], 0, 0, 0);
      }
    }
    __syncthreads();
  }
  #pragma unroll
  for (int rt=0; rt<4; rt++) {
    #pragma unroll
    for (int ct=0; ct<2; ct++) {
      int col = wv*32 + ct*16 + (lane & 15);
      int rbase = rt*16 + (lane >> 4)*4;
      sY[(rbase+0)*132 + col] = acc[rt][ct].x;
      sY[(rbase+1)*132 + col] = acc[rt][ct].y;
      sY[(rbase+2)*132 + col] = acc[rt][ct].z;
      sY[(rbase+3)*132 + col] = acc[rt][ct].w;
    }
  }
  __syncthreads();
  if (storeY) {
    for (int e = tid; e < 2048; e += 256) {
      int m = e >> 5, c4 = (e & 31)*4;
      float4 v = *reinterpret_cast<const float4*>(&sY[m*132 + c4]);
      *reinterpret_cast<float4*>(&Y[((size_t)(bt0 + (m>>5))*Cc + (m&31))*Nn + n0 + c4]) = v;
    }
  }
  {
    int tx = tid & 31, ty = tid >> 5;
    for (int btl = 0; btl < 2; btl++) {
      float og[4][4];
      #pragma unroll
      for (int i=0;i<4;i++) { og[i][0]=0.f; og[i][1]=0.f; og[i][2]=0.f; og[i][3]=0.f; }
      #pragma unroll 8
      for (int c = 0; c < 32; c++) {
        float4 yv = *reinterpret_cast<const float4*>(&sY[(btl*32 + c)*132 + tx*4]);
        float w0 = sW[((ty<<2)+0)*32 + c];
        float w1 = sW[((ty<<2)+1)*32 + c];
        float w2 = sW[((ty<<2)+2)*32 + c];
        float w3 = sW[((ty<<2)+3)*32 + c];
        og[0][0]+=w0*yv.x; og[0][1]+=w0*yv.y; og[0][2]+=w0*yv.z; og[0][3]+=w0*yv.w;
        og[1][0]+=w1*yv.x; og[1][1]+=w1*yv.y; og[1][2]+=w1*yv.z; og[1][3]+=w1*yv.w;
        og[2][0]+=w2*yv.x; og[2][1]+=w2*yv.y; og[2][2]+=w2*yv.z; og[2][3]+=w2*yv.w;
        og[3][0]+=w3*yv.x; og[3][1]+=w3*yv.y; og[3][2]+=w3*yv.z; og[3][3]+=w3*yv.w;
      }
      float* gp = gout + (size_t)(bt0+btl)*Cc*Nn + n0 + (tx<<2);
      #pragma unroll
      for (int i=0;i<4;i++) {
        float4 cur = *reinterpret_cast<float4*>(gp + (size_t)((ty<<2)+i)*Nn);
        cur.x += og[i][0]; cur.y += og[i][1]; cur.z += og[i][2]; cur.w += og[i][3];
        *reinterpret_cast<float4*>(gp + (size_t)((ty<<2)+i)*Nn) = cur;
      }
    }
  }
#undef MW
}

// ---------------- skip gather: skipK[b,k,c,t] (+)= xg_q[btl,c,node] ----------------
__global__ void k_skipgather(const float* __restrict__ xg, const int* __restrict__ miss,
                             float* __restrict__ skipK, int chunk, int first) {
  int idx = blockIdx.x*256 + threadIdx.x;
  if (idx >= BPC*Kk*Tt) return;
  int t = idx % Tt;
  int k = (idx / Tt) % Kk;
  int bloc = idx / (Tt*Kk);
  int bg = chunk*BPC + bloc;
  int node = miss[bg*Kk + k];
  const float* xp = xg + (((size_t)bloc*Tt + t)*Cc)*Nn + node;
  float* sp = skipK + (((size_t)bg*Kk + k)*Cc)*Tt + t;
  #pragma unroll
  for (int c=0;c<32;c++) {
    float v = xp[(size_t)c*Nn];
    sp[(size_t)c*Tt] = first ? v : (sp[(size_t)c*Tt] + v);
  }
}

// ---------------- fused ingru + xfold: Xs = iw@gout + ib ; x += gout (one gout pass) ----------------
__global__ void k_ingruxf(const float* __restrict__ gout, const float* __restrict__ iw,
                          const float* __restrict__ ib2, float* __restrict__ Xs,
                          float* __restrict__ x, int chunk) {
  size_t idx = (size_t)blockIdx.x*256 + threadIdx.x;
  if (idx >= BTNc) return;
  int n = idx & 511;
  size_t btl = idx >> 9;
  int b = chunk*BPC + (int)(btl / Tt), t = (int)(btl % Tt);
  const float* gp = gout + btl*Cc*Nn + n;
  float* xp = x + ((size_t)chunk*BTc + btl)*Cc*Nn + n;
  float s = ib2[0];
  #pragma unroll
  for (int c=0;c<Cc;c++) {
    float g = gp[(size_t)c*Nn];
    s += iw[c]*g;
    xp[(size_t)c*Nn] += g;
  }
  Xs[((size_t)t*Bb + b)*Nn + n] = s;
}

// ---------------- GRU v8: tag-embedded publication (seqlock-style), 1 RT per phase ----------------
// Producer packs 3 data floats + monotone tag into every aligned 16B store (one dwordx4 =
// one coherence-point transaction; tag fresh => its 3 floats fresh). Consumer lane q polls
// producer q's slot with parallel bypass loads and accepts when ALL embedded tags >= target —
// removes the second serial RT (flag->data) and the producer-side drain+flagstore.
__launch_bounds__(512, 1)
__global__ void k_gru8(const float* __restrict__ Xs, const float* __restrict__ input,
                       const float* __restrict__ wpack,
                       const float* __restrict__ zb, const float* __restrict__ rb,
                       const float* __restrict__ hb,
                       float* __restrict__ pubXH,   // [b][sl][PUBW]: xin(8)+h(8)+tags
                       float* __restrict__ pubRH,   // [b][sl][PUBW]: rh(8)+tags
                       float* __restrict__ outs) {
  __shared__ float wl[8*3072];   // 96KB weights
  __shared__ float xhl[8*1024];  // 32KB [b][xin|h]
  __shared__ float rhl[8*512];   // 16KB [b][rh]
  const int tid = threadIdx.x;
  const int sl  = blockIdx.x;
  const int n0  = sl*8;
  const int b   = tid >> 6;      // wave = batch
  const int q   = tid & 63;

  {
    const float4* src = reinterpret_cast<const float4*>(wpack + (size_t)sl*24576);
    float4* dst = reinterpret_cast<float4*>(wl);
    #pragma unroll 4
    for (int i = tid; i < 6144; i += 512) dst[i] = src[i];
  }
  __syncthreads();

  float zbv[8], rbv[8], hbv[8];
  #pragma unroll
  for (int c=0;c<8;c++) { zbv[c]=zb[n0+c]; rbv[c]=rb[n0+c]; hbv[c]=hb[n0+c]; }

  float hold[8];
  #pragma unroll
  for (int c=0;c<8;c++) hold[c] = 0.f;

  // t=0 init publish: xin = sigm(Xs0*M0), h = 0, tag = 1
  {
    float v[16];
    #pragma unroll
    for (int c=0;c<8;c++) {
      float Xi = Xs[(size_t)b*Nn + n0 + c];
      float Mi = input[(((size_t)b*7+1)*Tt + 0)*Nn + n0 + c];
      v[c]   = sigm(Xi*Mi);
      v[8+c] = 0.f;
    }
    if (q == 0) publish16(pubXH + ((size_t)b*64 + sl)*PUBW, v, 1);
  }

  float* xb  = xhl + b*1024;
  float* rlb = rhl + b*512;
  const float* pXH = pubXH + ((size_t)b*64 + q)*PUBW;   // lane q polls producer q
  const float* pRH = pubRH + ((size_t)b*64 + q)*PUBW;
  float* mXH = pubXH + ((size_t)b*64 + sl)*PUBW;
  float* mRH = pubRH + ((size_t)b*64 + sl)*PUBW;

  for (int t = 0; t < Tt; t++) {
    const unsigned tgt = (unsigned)(t + 1);
    // prefetch next-step Xs/M (regular cached loads)
    float4 xiA, xiB, miA, miB;
    {
      int tp = (t+1 < Tt) ? (t+1) : t;
      const float* xsp = Xs + ((size_t)tp*Bb + b)*Nn + n0;
      const float* mip = input + (((size_t)b*7+1)*Tt + tp)*Nn + n0;
      xiA = *reinterpret_cast<const float4*>(xsp);
      xiB = *reinterpret_cast<const float4*>(xsp + 4);
      miA = *reinterpret_cast<const float4*>(mip);
      miB = *reinterpret_cast<const float4*>(mip + 4);
    }
    // ---- poll xin|h (tags embedded; data arrives with validity) ----
    f32x4 u0,u1,u2,u3,u4,u5;
    for (;;) {
      asm volatile(
        "global_load_dwordx4 %0, %6, off sc0 sc1\n\t"
        "global_load_dwordx4 %1, %6, off offset:16 sc0 sc1\n\t"
        "global_load_dwordx4 %2, %6, off offset:32 sc0 sc1\n\t"
        "global_load_dwordx4 %3, %6, off offset:48 sc0 sc1\n\t"
        "global_load_dwordx4 %4, %6, off offset:64 sc0 sc1\n\t"
        "global_load_dwordx4 %5, %6, off offset:80 sc0 sc1\n\t"
        "s_waitcnt vmcnt(0)"
        : "=&v"(u0),"=&v"(u1),"=&v"(u2),"=&v"(u3),"=&v"(u4),"=&v"(u5)
        : "v"(pXH) : "memory");
      bool stale = (__float_as_uint(u0.w) < tgt) | (__float_as_uint(u1.w) < tgt) |
                   (__float_as_uint(u2.w) < tgt) | (__float_as_uint(u3.w) < tgt) |
                   (__float_as_uint(u4.w) < tgt) | (__float_as_uint(u5.w) < tgt);
      if (!__any(stale)) break;
      __builtin_amdgcn_s_sleep(1);
    }
    // unpack (lane q holds producer q's 16 values) -> per-wave LDS transpose
    {
      f32x4 a0 = {u0.x,u0.y,u0.z,u1.x};     // xin[0..3]
      f32x4 a1 = {u1.y,u1.z,u2.x,u2.y};     // xin[4..7]
      f32x4 a2 = {u2.z,u3.x,u3.y,u3.z};     // h[0..3]
      f32x4 a3 = {u4.x,u4.y,u4.z,u5.x};     // h[4..7]
      *reinterpret_cast<f32x4*>(&xb[q*8])         = a0;
      *reinterpret_cast<f32x4*>(&xb[q*8 + 4])     = a1;
      *reinterpret_cast<f32x4*>(&xb[512 + q*8])   = a2;
      *reinterpret_cast<f32x4*>(&xb[512 + q*8+4]) = a3;
    }
    asm volatile("s_waitcnt lgkmcnt(0)" ::: "memory");
    __builtin_amdgcn_sched_barrier(0);
    // ---- phase A: z, r (K=1024), hx (K=512) ----
    float az[8], ar[8], ax[8];
    #pragma unroll
    for (int c=0;c<8;c++) { az[c]=0.f; ar[c]=0.f; ax[c]=0.f; }
    #pragma unroll
    for (int i = 0; i < 8; i++) {
      int k = i*128 + q*2;
      float2 xv = *reinterpret_cast<const float2*>(xb + k);
      #pragma unroll
      for (int c = 0; c < 8; c++) {
        float2 wz = *reinterpret_cast<const float2*>(wl + c*3072 + k);
        float2 wr = *reinterpret_cast<const float2*>(wl + c*3072 + 1024 + k);
        az[c] += xv.x*wz.x + xv.y*wz.y;
        ar[c] += xv.x*wr.x + xv.y*wr.y;
      }
    }
    #pragma unroll
    for (int i = 0; i < 4; i++) {
      int k = i*128 + q*2;
      float2 xv = *reinterpret_cast<const float2*>(xb + k);
      #pragma unroll
      for (int c = 0; c < 8; c++) {
        float2 wx = *reinterpret_cast<const float2*>(wl + c*3072 + 2048 + k);
        ax[c] += xv.x*wx.x + xv.y*wx.y;
      }
    }
    #pragma unroll
    for (int d = 1; d < 64; d <<= 1) {
      #pragma unroll
      for (int c = 0; c < 8; c++) {
        az[c] += __shfl_xor(az[c], d);
        ar[c] += __shfl_xor(ar[c], d);
        ax[c] += __shfl_xor(ax[c], d);
      }
    }
    float zs[8], rh[8];
    #pragma unroll
    for (int c = 0; c < 8; c++) {
      zs[c] = sigm(az[c] + zbv[c]);
      float r = sigm(ar[c] + rbv[c]);
      rh[c] = r * hold[c];
    }
    if (q == 0) {
      float ft = __uint_as_float(tgt);
      f32x4 r0 = {rh[0],rh[1],rh[2],ft};
      f32x4 r1 = {rh[3],rh[4],rh[5],ft};
      f32x4 r2 = {rh[6],rh[7],0.f,ft};
      byp_store4(mRH,     r0);
      byp_store4(mRH + 4, r1);
      byp_store4(mRH + 8, r2);
    }
    // ---- poll rh ----
    f32x4 w0,w1,w2;
    for (;;) {
      asm volatile(
        "global_load_dwordx4 %0, %3, off sc0 sc1\n\t"
        "global_load_dwordx4 %1, %3, off offset:16 sc0 sc1\n\t"
        "global_load_dwordx4 %2, %3, off offset:32 sc0 sc1\n\t"
        "s_waitcnt vmcnt(0)"
        : "=&v"(w0),"=&v"(w1),"=&v"(w2)
        : "v"(pRH) : "memory");
      bool stale = (__float_as_uint(w0.w) < tgt) | (__float_as_uint(w1.w) < tgt) |
                   (__float_as_uint(w2.w) < tgt);
      if (!__any(stale)) break;
      __builtin_amdgcn_s_sleep(1);
    }
    {
      f32x4 e0 = {w0.x,w0.y,w0.z,w1.x};
      f32x4 e1 = {w1.y,w1.z,w2.x,w2.y};
      *reinterpret_cast<f32x4*>(&rlb[q*8])     = e0;
      *reinterpret_cast<f32x4*>(&rlb[q*8 + 4]) = e1;
    }
    asm volatile("s_waitcnt lgkmcnt(0)" ::: "memory");
    __builtin_amdgcn_sched_barrier(0);
    // ---- phase B: hh (K=512) + combine ----
    float ah[8];
    #pragma unroll
    for (int c=0;c<8;c++) ah[c]=0.f;
    #pragma unroll
    for (int i = 0; i < 4; i++) {
      int k = i*128 + q*2;
      float2 rv = *reinterpret_cast<const float2*>(rlb + k);
      #pragma unroll
      for (int c = 0; c < 8; c++) {
        float2 wh = *reinterpret_cast<const float2*>(wl + c*3072 + 2560 + k);
        ah[c] += rv.x*wh.x + rv.y*wh.y;
      }
    }
    #pragma unroll
    for (int d = 1; d < 64; d <<= 1) {
      #pragma unroll
      for (int c = 0; c < 8; c++) ah[c] += __shfl_xor(ah[c], d);
    }
    float hn[8];
    #pragma unroll
    for (int c = 0; c < 8; c++) {
      float ht = tanhf(ax[c] + ah[c] + hbv[c]);
      hn[c] = (1.f - zs[c])*hold[c] + zs[c]*ht;
    }
    if (q == 0) {
      f32x4 h0 = {hn[0],hn[1],hn[2],hn[3]};
      f32x4 h1 = {hn[4],hn[5],hn[6],hn[7]};
      *reinterpret_cast<f32x4*>(&outs[((size_t)t*Bb + b)*Nn + n0])     = h0;
      *reinterpret_cast<f32x4*>(&outs[((size_t)t*Bb + b)*Nn + n0 + 4]) = h1;
    }
    if (t+1 < Tt) {
      float v[16];
      v[0] = sigm(xiA.x*miA.x + hn[0]*(1.f - miA.x));
      v[1] = sigm(xiA.y*miA.y + hn[1]*(1.f - miA.y));
      v[2] = sigm(xiA.z*miA.z + hn[2]*(1.f - miA.z));
      v[3] = sigm(xiA.w*miA.w + hn[3]*(1.f - miA.w));
      v[4] = sigm(xiB.x*miB.x + hn[4]*(1.f - miB.x));
      v[5] = sigm(xiB.y*miB.y + hn[5]*(1.f - miB.y));
      v[6] = sigm(xiB.z*miB.z + hn[6]*(1.f - miB.z));
      v[7] = sigm(xiB.w*miB.w + hn[7]*(1.f - miB.w));
      #pragma unroll
      for (int c=0;c<8;c++) v[8+c] = hn[c];
      if (q == 0) publish16(mXH, v, t + 2);
    }
    #pragma unroll
    for (int c=0;c<8;c++) hold[c] = hn[c];
  }
}

// ---------------- x += outs*rw + rb (after GRU) ----------------
__global__ void k_xre(float* __restrict__ x, const float* __restrict__ outs,
                      const float* __restrict__ rw, const float* __restrict__ rb2) {
  size_t idx = (size_t)blockIdx.x*256 + threadIdx.x;
  if (idx >= BTCN) return;
  int n = idx & 511;
  int c = (int)((idx >> 9) & 31);
  size_t bt = idx >> 14;
  int b = (int)(bt / Tt), t = (int)(bt % Tt);
  float o = outs[((size_t)t*Bb + b)*Nn + n];
  x[idx] += o*rw[c] + rb2[c];
}

// ---------------- head: relu(skipK) -> end1 relu -> end2 ----------------
__launch_bounds__(256)
__global__ void k_head(const float* __restrict__ skipK,
                       const float* __restrict__ e1w, const float* __restrict__ e1b,
                       const float* __restrict__ e2w, const float* __restrict__ e2b,
                       float* __restrict__ out) {
  __shared__ float sw[2048], sb[64], s2[64];
  for (int l = threadIdx.x; l < 2048; l += 256) sw[l] = e1w[l];
  if (threadIdx.x < 64) { sb[threadIdx.x] = e1b[threadIdx.x]; s2[threadIdx.x] = e2w[threadIdx.x]; }
  __syncthreads();
  int idx = blockIdx.x*256 + threadIdx.x;
  if (idx >= Bb*Kk*Tt) return;
  int t = idx % Tt;
  int k = (idx / Tt) % Kk;
  int b = idx / (Tt*Kk);
  const float* sp = skipK + (((size_t)b*Kk + k)*Cc)*Tt + t;
  float in[32];
  #pragma unroll
  for (int c=0;c<32;c++) in[c] = fmaxf(sp[(size_t)c*Tt], 0.f);
  float acc = e2b[0];
  for (int o=0;o<64;o++) {
    float s = sb[o];
    #pragma unroll
    for (int c=0;c<32;c++) s += sw[o*32+c]*in[c];
    acc += s2[o]*fmaxf(s, 0.f);
  }
  out[idx] = acc;
}

extern "C" void kernel_launch(void* const* d_in, const int* in_sizes, int n_in,
                              void* d_out, int out_size, void* d_ws, size_t ws_size,
                              hipStream_t stream) {
  const float* input = (const float*)d_in[0];
  const int*   miss  = (const int*)  d_in[1];
  const float* sup0  = (const float*)d_in[2];
  const float* sup1  = (const float*)d_in[3];
  const float* nv1   = (const float*)d_in[4];
  const float* nv2   = (const float*)d_in[5];
  const float* skw   = (const float*)d_in[6];
  const float* skb   = (const float*)d_in[7];
  const float* fw    = (const float*)d_in[8];
  const float* fb    = (const float*)d_in[9];
  const float* gw    = (const float*)d_in[10];
  const float* gb    = (const float*)d_in[11];
  const float* gcw   = (const float*)d_in[12];
  const float* gcb   = (const float*)d_in[13];
  const float* iw    = (const float*)d_in[14];
  const float* ib2   = (const float*)d_in[15];
  const float* rw    = (const float*)d_in[16];
  const float* rb2   = (const float*)d_in[17];
  const float* zl    = (const float*)d_in[18];
  const float* zb    = (const float*)d_in[19];
  const float* rl    = (const float*)d_in[20];
  const float* rb    = (const float*)d_in[21];
  const float* hl    = (const float*)d_in[22];
  const float* hb    = (const float*)d_in[23];
  const float* e1w   = (const float*)d_in[24];
  const float* e1b   = (const float*)d_in[25];
  const float* e2w   = (const float*)d_in[26];
  const float* e2b   = (const float*)d_in[27];
  float* out = (float*)d_out;

  float* p     = (float*)d_ws;
  float* x     = p; p += BTCN;
  float* xg    = p; p += BTCNc;
  float* tmp1  = p; p += BTCNc;
  float* gout  = p; p += BTCNc;
  float* skipK = p; p += (size_t)Bb*Kk*Cc*Tt;
  float* adp   = p; p += (size_t)Nn*Nn;
  float* wpack = p; p += (size_t)GRUB*8*3072;
  unsigned short* ShiT = (unsigned short*)p; p += (size_t)(3*512*512)/2;
  unsigned short* SloT = (unsigned short*)p; p += (size_t)(3*512*512)/2;
  float* Xs    = p; p += (size_t)Tt*Bb*Nn;
  float* outs  = p; p += (size_t)Tt*Bb*Nn;
  float* pubXH = p; p += (size_t)Bb*GRUB*PUBW;
  float* pubRH = p; p += (size_t)Bb*GRUB*PUBW;

  k_wt2<<<(GRUB*8*3072 + 255)/256, 256, 0, stream>>>(zl, rl, hl, wpack);
  k_adp<<<Nn, 256, 0, stream>>>(nv1, nv2, adp);
  k_sprep<<<(3*512*512 + 255)/256, 256, 0, stream>>>(sup0, sup1, adp, ShiT, SloT);
  k_intransform<<<(int)((BTN + 255)/256), 256, 0, stream>>>(input, skw, skb, x);

  for (int layer = 0; layer < Ll; layer++) {
    for (int chunk = 0; chunk < NCH; chunk++) {
      k_fgconv<<<(int)((BTNc + 255)/256), 256, 0, stream>>>(
          x, fw + layer*2048, fb + layer*32, gw + layer*2048, gb + layer*32,
          gcw + layer*32*224, gcb + layer*32, xg, gout, chunk);
      for (int s = 0; s < 3; s++) {
        k_supmfma<<<dim3((BTc/2)*4), 256, 0, stream>>>(
            xg,   ShiT + s*262144, SloT + s*262144, gcw + layer*32*224, 2*s+1, tmp1, gout, 1);
        k_supmfma<<<dim3((BTc/2)*4), 256, 0, stream>>>(
            tmp1, ShiT + s*262144, SloT + s*262144, gcw + layer*32*224, 2*s+2, tmp1, gout, 0);
      }
      k_skipgather<<<(BPC*Kk*Tt + 255)/256, 256, 0, stream>>>(xg, miss, skipK, chunk, layer == 0 ? 1 : 0);
      k_ingruxf<<<(int)((BTNc + 255)/256), 256, 0, stream>>>(gout, iw, ib2, Xs, x, chunk);
    }
    (void)hipMemsetAsync(pubXH, 0, (size_t)Bb*GRUB*PUBW*2*sizeof(float), stream);
    k_gru8<<<dim3(GRUB), dim3(512), 0, stream>>>(
        Xs, input, wpack, zb, rb, hb, pubXH, pubRH, outs);
    k_xre<<<(int)((BTCN + 255)/256), 256, 0, stream>>>(x, outs, rw, rb2);
  }
  k_head<<<(Bb*Kk*Tt + 255)/256, 256, 0, stream>>>(skipK, e1w, e1b, e2w, e2b, out);
}

// Round 13
// 14972.623 us; speedup vs baseline: 1.1941x; 1.1941x over previous
//
#include <hip/hip_runtime.h>
#include <math.h>

#define Bb 8
#define Tt 168
#define Nn 512
#define Cc 32
#define Ll 4
#define Kk 50
#define NCH 4
#define BPC 2                     // batches per chunk (chunk boundary = t==0, no cross-chunk reads)
#define BTc (BPC*Tt)              // 336
#define BTNc ((size_t)BTc*Nn)
#define BTCNc ((size_t)BTc*Cc*Nn)
#define BT (Bb*Tt)
#define BTN ((size_t)Bb*Tt*Nn)
#define BTCN ((size_t)Bb*Tt*Cc*Nn)
#define GRUB 64                   // GRU blocks: each owns 8 output cols, all batches

typedef __attribute__((ext_vector_type(8))) short short8v;
typedef __attribute__((ext_vector_type(4))) float f32x4;
typedef __attribute__((ext_vector_type(2))) float f32x2;

__device__ __forceinline__ float sigm(float v) { return 1.0f/(1.0f + expf(-v)); }

__device__ __forceinline__ unsigned int f2bf(float x) {   // RNE, returns bits in low 16
  unsigned int u = __float_as_uint(x);
  u = u + 0x7FFFu + ((u >> 16) & 1u);
  return u >> 16;
}
__device__ __forceinline__ float bf2f(unsigned int h) {
  return __uint_as_float(h << 16);
}

__device__ __forceinline__ float sysload(const float* p) {
  return __hip_atomic_load(p, __ATOMIC_RELAXED, __HIP_MEMORY_SCOPE_SYSTEM);
}
__device__ __forceinline__ void sysstore(float* p, float v) {
  __hip_atomic_store(p, v, __ATOMIC_RELAXED, __HIP_MEMORY_SCOPE_SYSTEM);
}
__device__ __forceinline__ int flagload(const int* p) {
  return __hip_atomic_load(p, __ATOMIC_RELAXED, __HIP_MEMORY_SCOPE_AGENT);
}
__device__ __forceinline__ void flagstore(int* p, int v) {
  __hip_atomic_store(p, v, __ATOMIC_RELAXED, __HIP_MEMORY_SCOPE_AGENT);
}

// cache-bypassing vector store (coherence-point data plane)
__device__ __forceinline__ void byp_store4(float* p, f32x4 v) {
  asm volatile("global_store_dwordx4 %0, %1, off sc0 sc1" :: "v"(p), "v"(v) : "memory");
}

// ---------------- pack GRU weights block-sliced: wpack[sl][c][kk], kk over [z|r|hx|hh] ----------------
__global__ void k_wt2(const float* __restrict__ zl, const float* __restrict__ rl,
                      const float* __restrict__ hl, float* __restrict__ wpack) {
  int idx = blockIdx.x*256 + threadIdx.x;       // 64*8*3072 = 1572864
  if (idx >= GRUB*8*3072) return;
  int kk = idx % 3072;
  int c  = (idx / 3072) & 7;
  int sl = idx / (3072*8);
  int ncol = sl*8 + c;
  float v;
  if (kk < 1024)      v = zl[ncol*1024 + kk];
  else if (kk < 2048) v = rl[ncol*1024 + (kk-1024)];
  else if (kk < 2560) v = hl[ncol*1024 + (kk-2048)];
  else                v = hl[ncol*1024 + 512 + (kk-2560)];
  wpack[idx] = v;
}

// ---------------- adaptive adjacency: softmax(relu(nv1@nv2), axis=1) ----------------
__global__ void k_adp(const float* __restrict__ nv1, const float* __restrict__ nv2,
                      float* __restrict__ adp) {
  int i = blockIdx.x;
  __shared__ float row[512];
  __shared__ float red[256];
  float v1[10];
  #pragma unroll
  for (int k=0;k<10;k++) v1[k] = nv1[i*10+k];
  for (int jj = threadIdx.x; jj < 512; jj += 256) {
    float s = 0.f;
    #pragma unroll
    for (int k=0;k<10;k++) s += v1[k]*nv2[k*Nn + jj];
    row[jj] = fmaxf(s, 0.f);
  }
  __syncthreads();
  float m = fmaxf(row[threadIdx.x], row[threadIdx.x+256]);
  red[threadIdx.x] = m; __syncthreads();
  for (int s=128; s>0; s>>=1) { if (threadIdx.x < s) red[threadIdx.x] = fmaxf(red[threadIdx.x], red[threadIdx.x+s]); __syncthreads(); }
  float mx = red[0]; __syncthreads();
  float e0 = expf(row[threadIdx.x]      - mx);
  float e1 = expf(row[threadIdx.x+256]  - mx);
  red[threadIdx.x] = e0 + e1; __syncthreads();
  for (int s=128; s>0; s>>=1) { if (threadIdx.x < s) red[threadIdx.x] += red[threadIdx.x+s]; __syncthreads(); }
  float inv = 1.f/red[0];
  adp[(size_t)i*Nn + threadIdx.x]       = e0*inv;
  adp[(size_t)i*Nn + threadIdx.x + 256] = e1*inv;
}

// ---------------- split 3 matrices to transposed bf16 hi/lo (generic, slot base via ptrs) ----------------
__global__ void k_sprep(const float* __restrict__ S0, const float* __restrict__ S1,
                        const float* __restrict__ S2,
                        unsigned short* __restrict__ ShiT, unsigned short* __restrict__ SloT) {
  int idx = blockIdx.x*256 + threadIdx.x;
  if (idx >= 3*512*512) return;
  int s = idx >> 18;
  int rem = idx & 262143;
  int n = rem >> 9, k = rem & 511;
  const float* S = (s==0) ? S0 : (s==1) ? S1 : S2;
  float v = S[k*512 + n];
  unsigned int h = f2bf(v);
  float lo = v - bf2f(h);
  ShiT[idx] = (unsigned short)h;
  SloT[idx] = (unsigned short)f2bf(lo);
}

// ---------------- A2_s = A_s @ A_s (split-bf16 MFMA, fp32 out) ----------------
// A-operand: A[k][m] fp32 rows (on-the-fly split); B-operand: ShiT slot s ([n][m] bf16).
__launch_bounds__(256)
__global__ void k_aa(const float* __restrict__ sup0, const float* __restrict__ sup1,
                     const float* __restrict__ adp,
                     const unsigned short* __restrict__ ShiT6,
                     const unsigned short* __restrict__ SloT6,
                     float* __restrict__ A2) {
  __shared__ unsigned char smem[64*132*4];
  unsigned short* sXhi = (unsigned short*)smem;
  unsigned short* sXlo = sXhi + 2560;
  unsigned short* sShi = sXlo + 2560;
  unsigned short* sSlo = sShi + 5120;
  float* sY = (float*)smem;
#define MW 40
  const int tid  = threadIdx.x;
  const int bx   = blockIdx.x;
  const int s    = bx >> 5;            // 3 supports x 32 tiles
  const int r    = bx & 31;
  const int row0 = (r >> 2) * 64;
  const int n0   = (r & 3) * 128;
  const int lane = tid & 63, wv = tid >> 6;
  const int kb   = (lane >> 4)*8;
  const float* A = (s==0) ? sup0 : (s==1) ? sup1 : adp;
  const unsigned short* Shi = ShiT6 + (size_t)s*262144;
  const unsigned short* Slo = SloT6 + (size_t)s*262144;

  f32x4 acc[4][2];
  #pragma unroll
  for (int i=0;i<4;i++)
    #pragma unroll
    for (int j=0;j<2;j++) acc[i][j] = (f32x4){0.f,0.f,0.f,0.f};

  const int sm  = tid >> 2;
  const int skp = (tid & 3)*8;
  const size_t arow = (size_t)(row0 + sm)*512;
  const int sn  = tid >> 1;
  const int shp = (tid & 1)*16;

  for (int kc = 0; kc < 16; kc++) {
    const int k0 = kc*32;
    {
      float4 a0 = *reinterpret_cast<const float4*>(&A[arow + k0 + skp]);
      float4 a1 = *reinterpret_cast<const float4*>(&A[arow + k0 + skp + 4]);
      float v[8] = {a0.x,a0.y,a0.z,a0.w,a1.x,a1.y,a1.z,a1.w};
      unsigned int h[8], l[8];
      #pragma unroll
      for (int i=0;i<8;i++) { h[i] = f2bf(v[i]); l[i] = f2bf(v[i] - bf2f(h[i])); }
      uint4 H = { h[0]|(h[1]<<16), h[2]|(h[3]<<16), h[4]|(h[5]<<16), h[6]|(h[7]<<16) };
      uint4 L = { l[0]|(l[1]<<16), l[2]|(l[3]<<16), l[4]|(l[5]<<16), l[6]|(l[7]<<16) };
      *reinterpret_cast<uint4*>(&sXhi[sm*MW + skp]) = H;
      *reinterpret_cast<uint4*>(&sXlo[sm*MW + skp]) = L;
    }
    {
      const size_t srow = (size_t)(n0 + sn)*512 + k0 + shp;
      *reinterpret_cast<uint4*>(&sShi[sn*MW + shp])     = *reinterpret_cast<const uint4*>(&Shi[srow]);
      *reinterpret_cast<uint4*>(&sShi[sn*MW + shp + 8]) = *reinterpret_cast<const uint4*>(&Shi[srow + 8]);
      *reinterpret_cast<uint4*>(&sSlo[sn*MW + shp])     = *reinterpret_cast<const uint4*>(&Slo[srow]);
      *reinterpret_cast<uint4*>(&sSlo[sn*MW + shp + 8]) = *reinterpret_cast<const uint4*>(&Slo[srow + 8]);
    }
    __syncthreads();
    short8v bhi[2], blo[2];
    #pragma unroll
    for (int ct=0; ct<2; ct++) {
      int col = wv*32 + ct*16 + (lane & 15);
      bhi[ct] = *reinterpret_cast<const short8v*>(&sShi[col*MW + kb]);
      blo[ct] = *reinterpret_cast<const short8v*>(&sSlo[col*MW + kb]);
    }
    #pragma unroll
    for (int rt=0; rt<4; rt++) {
      int row = rt*16 + (lane & 15);
      short8v ahi = *reinterpret_cast<const short8v*>(&sXhi[row*MW + kb]);
      short8v alo = *reinterpret_cast<const short8v*>(&sXlo[row*MW + kb]);
      #pragma unroll
      for (int ct=0; ct<2; ct++) {
        acc[rt][ct] = __builtin_amdgcn_mfma_f32_16x16x32_bf16(ahi, bhi[ct], acc[rt][ct], 0, 0, 0);
        acc[rt][ct] = __builtin_amdgcn_mfma_f32_16x16x32_bf16(ahi, blo[ct], acc[rt][ct], 0, 0, 0);
        acc[rt][ct] = __builtin_amdgcn_mfma_f32_16x16x32_bf16(alo, bhi[ct], acc[rt][ct], 0, 0, 0);
      }
    }
    __syncthreads();
  }
  #pragma unroll
  for (int rt=0; rt<4; rt++) {
    #pragma unroll
    for (int ct=0; ct<2; ct++) {
      int col = wv*32 + ct*16 + (lane & 15);
      int rbase = rt*16 + (lane >> 4)*4;
      sY[(rbase+0)*132 + col] = acc[rt][ct].x;
      sY[(rbase+1)*132 + col] = acc[rt][ct].y;
      sY[(rbase+2)*132 + col] = acc[rt][ct].z;
      sY[(rbase+3)*132 + col] = acc[rt][ct].w;
    }
  }
  __syncthreads();
  for (int e = tid; e < 2048; e += 256) {
    int m = e >> 5, c4 = (e & 31)*4;
    float4 v = *reinterpret_cast<const float4*>(&sY[m*132 + c4]);
    *reinterpret_cast<float4*>(&A2[(size_t)s*262144 + (size_t)(row0 + m)*512 + n0 + c4]) = v;
  }
#undef MW
}

// ---------------- input transform: x = conv1x1(input[[0,3,5,6]]) -> (B,T,C,N) ----------------
__global__ void k_intransform(const float* __restrict__ input, const float* __restrict__ skw,
                              const float* __restrict__ skb, float* __restrict__ x) {
  size_t idx = (size_t)blockIdx.x*256 + threadIdx.x;
  if (idx >= BTN) return;
  int n = idx & 511;
  size_t bt = idx >> 9;
  int b = (int)(bt / Tt), t = (int)(bt % Tt);
  size_t chs = (size_t)Tt*Nn;
  size_t base = (((size_t)b*7)*Tt + t)*Nn + n;
  float v0 = input[base + 0*chs];
  float v3 = input[base + 3*chs];
  float v5 = input[base + 5*chs];
  float v6 = input[base + 6*chs];
  float* xp = x + bt*Cc*Nn + n;
  #pragma unroll
  for (int c=0;c<32;c++)
    xp[(size_t)c*Nn] = skb[c] + skw[c*4+0]*v0 + skw[c*4+1]*v3 + skw[c*4+2]*v5 + skw[c*4+3]*v6;
}

// ---------------- fused filter/gate conv1x2 -> xg_q ; gout_q = W0@xg + bias (chunk-local) ----------------
__launch_bounds__(256)
__global__ void k_fgconv(const float* __restrict__ x, const float* __restrict__ fw,
                         const float* __restrict__ fb, const float* __restrict__ gw,
                         const float* __restrict__ gb, const float* __restrict__ gcwl,
                         const float* __restrict__ gcb,
                         float* __restrict__ xg, float* __restrict__ gout, int chunk) {
  __shared__ float sfw[2048], sgw[2048], sw0[1024], sfb[32], sgb[32], sgcb[32];
  for (int l = threadIdx.x; l < 2048; l += 256) { sfw[l] = fw[l]; sgw[l] = gw[l]; }
  for (int l = threadIdx.x; l < 1024; l += 256) sw0[l] = gcwl[(l>>5)*224 + (l&31)];
  if (threadIdx.x < 32) {
    sfb[threadIdx.x] = fb[threadIdx.x];
    sgb[threadIdx.x] = gb[threadIdx.x];
    sgcb[threadIdx.x] = gcb[threadIdx.x];
  }
  __syncthreads();
  size_t idx = (size_t)blockIdx.x*256 + threadIdx.x;
  if (idx >= BTNc) return;
  int n = idx & 511;
  size_t btl = idx >> 9;
  int t = (int)(btl % Tt);
  size_t btg = (size_t)chunk*BTc + btl;
  const float* xp = x + btg*Cc*Nn + n;
  float xl[32], xr[32];
  #pragma unroll
  for (int c=0;c<32;c++) xr[c] = xp[(size_t)c*Nn];
  if (t == 0) {
    #pragma unroll
    for (int c=0;c<32;c++) xl[c] = 0.f;
  } else {
    const float* xq = xp - (size_t)Cc*Nn;
    #pragma unroll
    for (int c=0;c<32;c++) xl[c] = xq[(size_t)c*Nn];
  }
  float xgv[32];
  for (int c=0;c<32;c++) {
    float f = sfb[c], g = sgb[c];
    #pragma unroll
    for (int cp=0;cp<32;cp++) {
      f += xl[cp]*sfw[(c*32+cp)*2] + xr[cp]*sfw[(c*32+cp)*2+1];
      g += xl[cp]*sgw[(c*32+cp)*2] + xr[cp]*sgw[(c*32+cp)*2+1];
    }
    xgv[c] = tanhf(f) * sigm(g);
  }
  float* xgp = xg + btl*Cc*Nn + n;
  #pragma unroll
  for (int c=0;c<32;c++) xgp[(size_t)c*Nn] = xgv[c];
  float* gp = gout + btl*Cc*Nn + n;
  for (int o=0;o<32;o++) {
    float s = sgcb[o];
    #pragma unroll
    for (int c=0;c<32;c++) s += sw0[o*32+c]*xgv[c];
    gp[(size_t)o*Nn] = s;
  }
}

// ---------------- all-support GEMM: gout += sum over 6 pairs W_p @ (X @ panel_p) ----------------
// panel_p: p=(s,j): j=0 -> A_s (slot s), j=1 -> A2_s (slot 3+s); W_p = gcw slot p+1.
// 6 independent products accumulated in persistent register og; single gout RMW.
__launch_bounds__(256)
__global__ void k_supall(const float* __restrict__ X,
                         const unsigned short* __restrict__ ShiT6,
                         const unsigned short* __restrict__ SloT6,
                         const float* __restrict__ gcw,
                         float* __restrict__ gout) {
  __shared__ unsigned char smem[64*132*4];      // staging pool / sY
  __shared__ float sW[6*1024];
  unsigned short* sXhi = (unsigned short*)smem;
  unsigned short* sXlo = sXhi + 2560;
  unsigned short* sShi = sXlo + 2560;
  unsigned short* sSlo = sShi + 5120;
  float* sY = (float*)smem;
#define MW 40
  const int tid  = threadIdx.x;
  const int bt2  = blockIdx.x >> 2;
  const int colg = blockIdx.x & 3;
  const int bt0  = bt2*2;
  const int n0   = colg*128;
  const int lane = tid & 63, wv = tid >> 6;
  const int kb   = (lane >> 4)*8;

  for (int l = tid; l < 6144; l += 256) {
    int p = l >> 10, idx = l & 1023;
    sW[l] = gcw[(idx>>5)*224 + (p+1)*32 + (idx&31)];
  }

  const int sm  = tid >> 2;
  const int skp = (tid & 3)*8;
  const size_t xrow = ((size_t)(bt0 + (sm>>5))*Cc + (sm&31))*Nn;
  const int sn  = tid >> 1;
  const int shp = (tid & 1)*16;
  const int tx = tid & 31, ty = tid >> 5;

  float og[2][4][4];
  #pragma unroll
  for (int bl=0;bl<2;bl++)
    #pragma unroll
    for (int i=0;i<4;i++)
      #pragma unroll
      for (int j=0;j<4;j++) og[bl][i][j] = 0.f;

  for (int p = 0; p < 6; p++) {
    const int s = p >> 1, j = p & 1;
    const int panel = j ? (3 + s) : s;
    const unsigned short* Shi = ShiT6 + (size_t)panel*262144;
    const unsigned short* Slo = SloT6 + (size_t)panel*262144;

    f32x4 acc[4][2];
    #pragma unroll
    for (int i=0;i<4;i++)
      #pragma unroll
      for (int jj=0;jj<2;jj++) acc[i][jj] = (f32x4){0.f,0.f,0.f,0.f};

    for (int kc = 0; kc < 16; kc++) {
      const int k0 = kc*32;
      {
        float4 a0 = *reinterpret_cast<const float4*>(&X[xrow + k0 + skp]);
        float4 a1 = *reinterpret_cast<const float4*>(&X[xrow + k0 + skp + 4]);
        float v[8] = {a0.x,a0.y,a0.z,a0.w,a1.x,a1.y,a1.z,a1.w};
        unsigned int h[8], l[8];
        #pragma unroll
        for (int i=0;i<8;i++) { h[i] = f2bf(v[i]); l[i] = f2bf(v[i] - bf2f(h[i])); }
        uint4 H = { h[0]|(h[1]<<16), h[2]|(h[3]<<16), h[4]|(h[5]<<16), h[6]|(h[7]<<16) };
        uint4 L = { l[0]|(l[1]<<16), l[2]|(l[3]<<16), l[4]|(l[5]<<16), l[6]|(l[7]<<16) };
        *reinterpret_cast<uint4*>(&sXhi[sm*MW + skp]) = H;
        *reinterpret_cast<uint4*>(&sXlo[sm*MW + skp]) = L;
      }
      {
        const size_t srow = (size_t)(n0 + sn)*512 + k0 + shp;
        *reinterpret_cast<uint4*>(&sShi[sn*MW + shp])     = *reinterpret_cast<const uint4*>(&Shi[srow]);
        *reinterpret_cast<uint4*>(&sShi[sn*MW + shp + 8]) = *reinterpret_cast<const uint4*>(&Shi[srow + 8]);
        *reinterpret_cast<uint4*>(&sSlo[sn*MW + shp])     = *reinterpret_cast<const uint4*>(&Slo[srow]);
        *reinterpret_cast<uint4*>(&sSlo[sn*MW + shp + 8]) = *reinterpret_cast<const uint4*>(&Slo[srow + 8]);
      }
      __syncthreads();
      short8v bhi[2], blo[2];
      #pragma unroll
      for (int ct=0; ct<2; ct++) {
        int col = wv*32 + ct*16 + (lane & 15);
        bhi[ct] = *reinterpret_cast<const short8v*>(&sShi[col*MW + kb]);
        blo[ct] = *reinterpret_cast<const short8v*>(&sSlo[col*MW + kb]);
      }
      #pragma unroll
      for (int rt=0; rt<4; rt++) {
        int row = rt*16 + (lane & 15);
        short8v ahi = *reinterpret_cast<const short8v*>(&sXhi[row*MW + kb]);
        short8v alo = *reinterpret_cast<const short8v*>(&sXlo[row*MW + kb]);
        #pragma unroll
        for (int ct=0; ct<2; ct++) {
          acc[rt][ct] = __builtin_amdgcn_mfma_f32_16x16x32_bf16(ahi, bhi[ct], acc[rt][ct], 0, 0, 0);
          acc[rt][ct] = __builtin_amdgcn_mfma_f32_16x16x32_bf16(ahi, blo[ct], acc[rt][ct], 0, 0, 0);
          acc[rt][ct] = __builtin_amdgcn_mfma_f32_16x16x32_bf16(alo, bhi[ct], acc[rt][ct], 0, 0, 0);
        }
      }
      __syncthreads();
    }
    // acc -> sY
    #pragma unroll
    for (int rt=0; rt<4; rt++) {
      #pragma unroll
      for (int ct=0; ct<2; ct++) {
        int col = wv*32 + ct*16 + (lane & 15);
        int rbase = rt*16 + (lane >> 4)*4;
        sY[(rbase+0)*132 + col] = acc[rt][ct].x;
        sY[(rbase+1)*132 + col] = acc[rt][ct].y;
        sY[(rbase+2)*132 + col] = acc[rt][ct].z;
        sY[(rbase+3)*132 + col] = acc[rt][ct].w;
      }
    }
    __syncthreads();
    // W-mix accumulate into persistent og
    for (int btl = 0; btl < 2; btl++) {
      #pragma unroll 8
      for (int c = 0; c < 32; c++) {
        float4 yv = *reinterpret_cast<const float4*>(&sY[(btl*32 + c)*132 + tx*4]);
        float w0 = sW[p*1024 + ((ty<<2)+0)*32 + c];
        float w1 = sW[p*1024 + ((ty<<2)+1)*32 + c];
        float w2 = sW[p*1024 + ((ty<<2)+2)*32 + c];
        float w3 = sW[p*1024 + ((ty<<2)+3)*32 + c];
        og[btl][0][0]+=w0*yv.x; og[btl][0][1]+=w0*yv.y; og[btl][0][2]+=w0*yv.z; og[btl][0][3]+=w0*yv.w;
        og[btl][1][0]+=w1*yv.x; og[btl][1][1]+=w1*yv.y; og[btl][1][2]+=w1*yv.z; og[btl][1][3]+=w1*yv.w;
        og[btl][2][0]+=w2*yv.x; og[btl][2][1]+=w2*yv.y; og[btl][2][2]+=w2*yv.z; og[btl][2][3]+=w2*yv.w;
        og[btl][3][0]+=w3*yv.x; og[btl][3][1]+=w3*yv.y; og[btl][3][2]+=w3*yv.z; og[btl][3][3]+=w3*yv.w;
      }
    }
    __syncthreads();   // sY reads done before next pair overwrites pool
  }
  // single gout RMW
  for (int btl = 0; btl < 2; btl++) {
    float* gp = gout + (size_t)(bt0+btl)*Cc*Nn + n0 + (tx<<2);
    #pragma unroll
    for (int i=0;i<4;i++) {
      float4 cur = *reinterpret_cast<float4*>(gp + (size_t)((ty<<2)+i)*Nn);
      cur.x += og[btl][i][0]; cur.y += og[btl][i][1]; cur.z += og[btl][i][2]; cur.w += og[btl][i][3];
      *reinterpret_cast<float4*>(gp + (size_t)((ty<<2)+i)*Nn) = cur;
    }
  }
#undef MW
}

// ---------------- skip gather: skipK[b,k,c,t] (+)= xg_q[btl,c,node] ----------------
__global__ void k_skipgather(const float* __restrict__ xg, const int* __restrict__ miss,
                             float* __restrict__ skipK, int chunk, int first) {
  int idx = blockIdx.x*256 + threadIdx.x;
  if (idx >= BPC*Kk*Tt) return;
  int t = idx % Tt;
  int k = (idx / Tt) % Kk;
  int bloc = idx / (Tt*Kk);
  int bg = chunk*BPC + bloc;
  int node = miss[bg*Kk + k];
  const float* xp = xg + (((size_t)bloc*Tt + t)*Cc)*Nn + node;
  float* sp = skipK + (((size_t)bg*Kk + k)*Cc)*Tt + t;
  #pragma unroll
  for (int c=0;c<32;c++) {
    float v = xp[(size_t)c*Nn];
    sp[(size_t)c*Tt] = first ? v : (sp[(size_t)c*Tt] + v);
  }
}

// ---------------- fused ingru + xfold: Xs = iw@gout + ib ; x += gout (one gout pass) ----------------
__global__ void k_ingruxf(const float* __restrict__ gout, const float* __restrict__ iw,
                          const float* __restrict__ ib2, float* __restrict__ Xs,
                          float* __restrict__ x, int chunk) {
  size_t idx = (size_t)blockIdx.x*256 + threadIdx.x;
  if (idx >= BTNc) return;
  int n = idx & 511;
  size_t btl = idx >> 9;
  int b = chunk*BPC + (int)(btl / Tt), t = (int)(btl % Tt);
  const float* gp = gout + btl*Cc*Nn + n;
  float* xp = x + ((size_t)chunk*BTc + btl)*Cc*Nn + n;
  float s = ib2[0];
  #pragma unroll
  for (int c=0;c<Cc;c++) {
    float g = gp[(size_t)c*Nn];
    s += iw[c]*g;
    xp[(size_t)c*Nn] += g;
  }
  Xs[((size_t)t*Bb + b)*Nn + n] = s;
}

// ---------------- GRU v7 (round-10 proven): wave-decoupled, per-batch flags ----------------
__launch_bounds__(512, 1)
__global__ void k_gru7(const float* __restrict__ Xs, const float* __restrict__ input,
                       const float* __restrict__ wpack,
                       const float* __restrict__ zb, const float* __restrict__ rb,
                       const float* __restrict__ hb,
                       float* __restrict__ xh_g,      // [b][ xin 0:512 | h 512:1024 ]
                       float* __restrict__ rh_g,      // [b][512]
                       float* __restrict__ outs,
                       int* __restrict__ flags) {     // [(b*64+sl)*32]
  __shared__ float wl[8*3072];   // 96KB weights only
  const int tid = threadIdx.x;
  const int sl  = blockIdx.x;
  const int n0  = sl*8;
  const int b   = tid >> 6;      // wave = batch
  const int q   = tid & 63;

  {
    const float4* src = reinterpret_cast<const float4*>(wpack + (size_t)sl*24576);
    float4* dst = reinterpret_cast<float4*>(wl);
    #pragma unroll 4
    for (int i = tid; i < 6144; i += 512) dst[i] = src[i];
  }
  if (q < 8) {
    int nn = n0 + q;
    float Xi = Xs[(size_t)b*Nn + nn];
    float Mi = input[(((size_t)b*7+1)*Tt + 0)*Nn + nn];
    sysstore(xh_g + b*1024 + 512 + nn, 0.f);
    sysstore(xh_g + b*1024 + nn, sigm(Xi*Mi));
  }
  __syncthreads();
  asm volatile("s_waitcnt vmcnt(0)" ::: "memory");
  if (q == 0) flagstore(flags + (b*64 + sl)*32, 1);

  const int* pollfl = flags + (b*64 + q)*32;
  int* myfl = flags + (b*64 + sl)*32;

  float zbv[8], rbv[8], hbv[8];
  #pragma unroll
  for (int c=0;c<8;c++) { zbv[c]=zb[n0+c]; rbv[c]=rb[n0+c]; hbv[c]=hb[n0+c]; }

  const float* bp = xh_g + b*1024;
  const float* rp = rh_g + b*512;

  for (int t = 0; t < Tt; t++) {
    float4 xiA, xiB, miA, miB;
    {
      int tp = (t+1 < Tt) ? (t+1) : t;
      const float* xsp = Xs + ((size_t)tp*Bb + b)*Nn + n0;
      const float* mip = input + (((size_t)b*7+1)*Tt + tp)*Nn + n0;
      xiA = *reinterpret_cast<const float4*>(xsp);
      xiB = *reinterpret_cast<const float4*>(xsp + 4);
      miA = *reinterpret_cast<const float4*>(mip);
      miB = *reinterpret_cast<const float4*>(mip + 4);
    }
    {
      int tgt = 1 + 2*t;
      while (!__all(flagload(pollfl) >= tgt)) __builtin_amdgcn_s_sleep(1);
    }
    f32x2 xv[8]; f32x4 h0v, h1v;
    asm volatile(
      "global_load_dwordx2 %0, %10, off sc0 sc1\n\t"
      "global_load_dwordx2 %1, %11, off sc0 sc1\n\t"
      "global_load_dwordx2 %2, %12, off sc0 sc1\n\t"
      "global_load_dwordx2 %3, %13, off sc0 sc1\n\t"
      "global_load_dwordx2 %4, %14, off sc0 sc1\n\t"
      "global_load_dwordx2 %5, %15, off sc0 sc1\n\t"
      "global_load_dwordx2 %6, %16, off sc0 sc1\n\t"
      "global_load_dwordx2 %7, %17, off sc0 sc1\n\t"
      "global_load_dwordx4 %8, %18, off sc0 sc1\n\t"
      "global_load_dwordx4 %9, %19, off sc0 sc1\n\t"
      "s_waitcnt vmcnt(0)"
      : "=&v"(xv[0]), "=&v"(xv[1]), "=&v"(xv[2]), "=&v"(xv[3]),
        "=&v"(xv[4]), "=&v"(xv[5]), "=&v"(xv[6]), "=&v"(xv[7]),
        "=&v"(h0v), "=&v"(h1v)
      : "v"(bp + 0*128 + q*2), "v"(bp + 1*128 + q*2), "v"(bp + 2*128 + q*2), "v"(bp + 3*128 + q*2),
        "v"(bp + 4*128 + q*2), "v"(bp + 5*128 + q*2), "v"(bp + 6*128 + q*2), "v"(bp + 7*128 + q*2),
        "v"(bp + 512 + n0), "v"(bp + 512 + n0 + 4)
      : "memory");
    float hold[8] = {h0v.x, h0v.y, h0v.z, h0v.w, h1v.x, h1v.y, h1v.z, h1v.w};
    float az[8], ar[8], ax[8];
    #pragma unroll
    for (int c=0;c<8;c++) { az[c]=0.f; ar[c]=0.f; ax[c]=0.f; }
    #pragma unroll
    for (int i = 0; i < 8; i++) {
      int k = i*128 + q*2;
      #pragma unroll
      for (int c = 0; c < 8; c++) {
        float2 wz = *reinterpret_cast<const float2*>(wl + c*3072 + k);
        float2 wr = *reinterpret_cast<const float2*>(wl + c*3072 + 1024 + k);
        az[c] += xv[i].x*wz.x + xv[i].y*wz.y;
        ar[c] += xv[i].x*wr.x + xv[i].y*wr.y;
      }
    }
    #pragma unroll
    for (int i = 0; i < 4; i++) {
      int k = i*128 + q*2;
      #pragma unroll
      for (int c = 0; c < 8; c++) {
        float2 wx = *reinterpret_cast<const float2*>(wl + c*3072 + 2048 + k);
        ax[c] += xv[i].x*wx.x + xv[i].y*wx.y;
      }
    }
    #pragma unroll
    for (int d = 1; d < 64; d <<= 1) {
      #pragma unroll
      for (int c = 0; c < 8; c++) {
        az[c] += __shfl_xor(az[c], d);
        ar[c] += __shfl_xor(ar[c], d);
        ax[c] += __shfl_xor(ax[c], d);
      }
    }
    float zs[8], rh[8];
    #pragma unroll
    for (int c = 0; c < 8; c++) {
      zs[c] = sigm(az[c] + zbv[c]);
      float r = sigm(ar[c] + rbv[c]);
      rh[c] = r * hold[c];
    }
    if (q == 0) {
      f32x4 r0 = {rh[0],rh[1],rh[2],rh[3]};
      f32x4 r1 = {rh[4],rh[5],rh[6],rh[7]};
      byp_store4(rh_g + b*512 + n0,     r0);
      byp_store4(rh_g + b*512 + n0 + 4, r1);
      asm volatile("s_waitcnt vmcnt(0)" ::: "memory");
      flagstore(myfl, 2 + 2*t);
    }
    {
      int tgt = 2 + 2*t;
      while (!__all(flagload(pollfl) >= tgt)) __builtin_amdgcn_s_sleep(1);
    }
    f32x2 rv[4];
    asm volatile(
      "global_load_dwordx2 %0, %4, off sc0 sc1\n\t"
      "global_load_dwordx2 %1, %5, off sc0 sc1\n\t"
      "global_load_dwordx2 %2, %6, off sc0 sc1\n\t"
      "global_load_dwordx2 %3, %7, off sc0 sc1\n\t"
      "s_waitcnt vmcnt(0)"
      : "=&v"(rv[0]), "=&v"(rv[1]), "=&v"(rv[2]), "=&v"(rv[3])
      : "v"(rp + 0*128 + q*2), "v"(rp + 1*128 + q*2), "v"(rp + 2*128 + q*2), "v"(rp + 3*128 + q*2)
      : "memory");
    float ah[8];
    #pragma unroll
    for (int c=0;c<8;c++) ah[c]=0.f;
    #pragma unroll
    for (int i = 0; i < 4; i++) {
      int k = i*128 + q*2;
      #pragma unroll
      for (int c = 0; c < 8; c++) {
        float2 wh = *reinterpret_cast<const float2*>(wl + c*3072 + 2560 + k);
        ah[c] += rv[i].x*wh.x + rv[i].y*wh.y;
      }
    }
    #pragma unroll
    for (int d = 1; d < 64; d <<= 1) {
      #pragma unroll
      for (int c = 0; c < 8; c++) ah[c] += __shfl_xor(ah[c], d);
    }
    float hn[8];
    #pragma unroll
    for (int c = 0; c < 8; c++) {
      float ht = tanhf(ax[c] + ah[c] + hbv[c]);
      hn[c] = (1.f - zs[c])*hold[c] + zs[c]*ht;
    }
    if (q == 0) {
      f32x4 h0 = {hn[0],hn[1],hn[2],hn[3]};
      f32x4 h1 = {hn[4],hn[5],hn[6],hn[7]};
      *reinterpret_cast<f32x4*>(&outs[((size_t)t*Bb + b)*Nn + n0])     = h0;
      *reinterpret_cast<f32x4*>(&outs[((size_t)t*Bb + b)*Nn + n0 + 4]) = h1;
      byp_store4(xh_g + b*1024 + 512 + n0,     h0);
      byp_store4(xh_g + b*1024 + 512 + n0 + 4, h1);
      if (t+1 < Tt) {
        f32x4 x0, x1;
        x0.x = sigm(xiA.x*miA.x + hn[0]*(1.f - miA.x));
        x0.y = sigm(xiA.y*miA.y + hn[1]*(1.f - miA.y));
        x0.z = sigm(xiA.z*miA.z + hn[2]*(1.f - miA.z));
        x0.w = sigm(xiA.w*miA.w + hn[3]*(1.f - miA.w));
        x1.x = sigm(xiB.x*miB.x + hn[4]*(1.f - miB.x));
        x1.y = sigm(xiB.y*miB.y + hn[5]*(1.f - miB.y));
        x1.z = sigm(xiB.z*miB.z + hn[6]*(1.f - miB.z));
        x1.w = sigm(xiB.w*miB.w + hn[7]*(1.f - miB.w));
        byp_store4(xh_g + b*1024 + n0,     x0);
        byp_store4(xh_g + b*1024 + n0 + 4, x1);
      }
      asm volatile("s_waitcnt vmcnt(0)" ::: "memory");
      flagstore(myfl, 3 + 2*t);
    }
  }
}

// ---------------- x += outs*rw + rb (after GRU) ----------------
__global__ void k_xre(float* __restrict__ x, const float* __restrict__ outs,
                      const float* __restrict__ rw, const float* __restrict__ rb2) {
  size_t idx = (size_t)blockIdx.x*256 + threadIdx.x;
  if (idx >= BTCN) return;
  int n = idx & 511;
  int c = (int)((idx >> 9) & 31);
  size_t bt = idx >> 14;
  int b = (int)(bt / Tt), t = (int)(bt % Tt);
  float o = outs[((size_t)t*Bb + b)*Nn + n];
  x[idx] += o*rw[c] + rb2[c];
}

// ---------------- head: relu(skipK) -> end1 relu -> end2 ----------------
__launch_bounds__(256)
__global__ void k_head(const float* __restrict__ skipK,
                       const float* __restrict__ e1w, const float* __restrict__ e1b,
                       const float* __restrict__ e2w, const float* __restrict__ e2b,
                       float* __restrict__ out) {
  __shared__ float sw[2048], sb[64], s2[64];
  for (int l = threadIdx.x; l < 2048; l += 256) sw[l] = e1w[l];
  if (threadIdx.x < 64) { sb[threadIdx.x] = e1b[threadIdx.x]; s2[threadIdx.x] = e2w[threadIdx.x]; }
  __syncthreads();
  int idx = blockIdx.x*256 + threadIdx.x;
  if (idx >= Bb*Kk*Tt) return;
  int t = idx % Tt;
  int k = (idx / Tt) % Kk;
  int b = idx / (Tt*Kk);
  const float* sp = skipK + (((size_t)b*Kk + k)*Cc)*Tt + t;
  float in[32];
  #pragma unroll
  for (int c=0;c<32;c++) in[c] = fmaxf(sp[(size_t)c*Tt], 0.f);
  float acc = e2b[0];
  for (int o=0;o<64;o++) {
    float s = sb[o];
    #pragma unroll
    for (int c=0;c<32;c++) s += sw[o*32+c]*in[c];
    acc += s2[o]*fmaxf(s, 0.f);
  }
  out[idx] = acc;
}

extern "C" void kernel_launch(void* const* d_in, const int* in_sizes, int n_in,
                              void* d_out, int out_size, void* d_ws, size_t ws_size,
                              hipStream_t stream) {
  const float* input = (const float*)d_in[0];
  const int*   miss  = (const int*)  d_in[1];
  const float* sup0  = (const float*)d_in[2];
  const float* sup1  = (const float*)d_in[3];
  const float* nv1   = (const float*)d_in[4];
  const float* nv2   = (const float*)d_in[5];
  const float* skw   = (const float*)d_in[6];
  const float* skb   = (const float*)d_in[7];
  const float* fw    = (const float*)d_in[8];
  const float* fb    = (const float*)d_in[9];
  const float* gw    = (const float*)d_in[10];
  const float* gb    = (const float*)d_in[11];
  const float* gcw   = (const float*)d_in[12];
  const float* gcb   = (const float*)d_in[13];
  const float* iw    = (const float*)d_in[14];
  const float* ib2   = (const float*)d_in[15];
  const float* rw    = (const float*)d_in[16];
  const float* rb2   = (const float*)d_in[17];
  const float* zl    = (const float*)d_in[18];
  const float* zb    = (const float*)d_in[19];
  const float* rl    = (const float*)d_in[20];
  const float* rb    = (const float*)d_in[21];
  const float* hl    = (const float*)d_in[22];
  const float* hb    = (const float*)d_in[23];
  const float* e1w   = (const float*)d_in[24];
  const float* e1b   = (const float*)d_in[25];
  const float* e2w   = (const float*)d_in[26];
  const float* e2b   = (const float*)d_in[27];
  float* out = (float*)d_out;

  float* p     = (float*)d_ws;
  float* x     = p; p += BTCN;
  float* xg    = p; p += BTCNc;
  float* gout  = p; p += BTCNc;
  float* skipK = p; p += (size_t)Bb*Kk*Cc*Tt;
  float* adp   = p; p += (size_t)Nn*Nn;
  float* A2    = p; p += (size_t)3*Nn*Nn;
  float* wpack = p; p += (size_t)GRUB*8*3072;
  unsigned short* ShiT6 = (unsigned short*)p; p += (size_t)(6*512*512)/2;
  unsigned short* SloT6 = (unsigned short*)p; p += (size_t)(6*512*512)/2;
  float* Xs    = p; p += (size_t)Tt*Bb*Nn;
  float* outs  = p; p += (size_t)Tt*Bb*Nn;
  float* xh_g  = p; p += Bb*1024;
  float* rh_g  = p; p += Bb*512;
  int*   flags = (int*)p; p += (size_t)Bb*GRUB*32;

  k_wt2<<<(GRUB*8*3072 + 255)/256, 256, 0, stream>>>(zl, rl, hl, wpack);
  k_adp<<<Nn, 256, 0, stream>>>(nv1, nv2, adp);
  k_sprep<<<(3*512*512 + 255)/256, 256, 0, stream>>>(sup0, sup1, adp, ShiT6, SloT6);
  k_aa<<<96, 256, 0, stream>>>(sup0, sup1, adp, ShiT6, SloT6, A2);
  k_sprep<<<(3*512*512 + 255)/256, 256, 0, stream>>>(A2, A2 + 262144, A2 + 524288,
                                                     ShiT6 + 3*262144, SloT6 + 3*262144);
  k_intransform<<<(int)((BTN + 255)/256), 256, 0, stream>>>(input, skw, skb, x);

  for (int layer = 0; layer < Ll; layer++) {
    for (int chunk = 0; chunk < NCH; chunk++) {
      k_fgconv<<<(int)((BTNc + 255)/256), 256, 0, stream>>>(
          x, fw + layer*2048, fb + layer*32, gw + layer*2048, gb + layer*32,
          gcw + layer*32*224, gcb + layer*32, xg, gout, chunk);
      k_supall<<<dim3((BTc/2)*4), 256, 0, stream>>>(
          xg, ShiT6, SloT6, gcw + layer*32*224, gout);
      k_skipgather<<<(BPC*Kk*Tt + 255)/256, 256, 0, stream>>>(xg, miss, skipK, chunk, layer == 0 ? 1 : 0);
      k_ingruxf<<<(int)((BTNc + 255)/256), 256, 0, stream>>>(gout, iw, ib2, Xs, x, chunk);
    }
    (void)hipMemsetAsync(flags, 0, (size_t)Bb*GRUB*32*sizeof(int), stream);
    k_gru7<<<dim3(GRUB), dim3(512), 0, stream>>>(
        Xs, input, wpack, zb, rb, hb, xh_g, rh_g, outs, flags);
    k_xre<<<(int)((BTCN + 255)/256), 256, 0, stream>>>(x, outs, rw, rb2);
  }
  k_head<<<(Bb*Kk*Tt + 255)/256, 256, 0, stream>>>(skipK, e1w, e1b, e2w, e2b, out);
}

// Round 15
// 10998.186 us; speedup vs baseline: 1.6256x; 1.3614x over previous
//
#include <hip/hip_runtime.h>
#include <math.h>

#define Bb 8
#define Tt 168
#define Nn 512
#define Cc 32
#define Ll 4
#define Kk 50
#define NCH 4
#define BPC 2                     // batches per chunk (chunk boundary = t==0, no cross-chunk reads)
#define BTc (BPC*Tt)              // 336
#define BTNc ((size_t)BTc*Nn)
#define BTCNc ((size_t)BTc*Cc*Nn)
#define BT (Bb*Tt)
#define BTN ((size_t)Bb*Tt*Nn)
#define BTCN ((size_t)Bb*Tt*Cc*Nn)
#define GRUB 64                   // GRU blocks: each owns 8 output cols, all batches

typedef __attribute__((ext_vector_type(8))) short short8v;
typedef __attribute__((ext_vector_type(4))) float f32x4;
typedef __attribute__((ext_vector_type(2))) float f32x2;

__device__ __forceinline__ float sigm(float v) { return 1.0f/(1.0f + expf(-v)); }

__device__ __forceinline__ unsigned int f2bf(float x) {   // RNE, returns bits in low 16
  unsigned int u = __float_as_uint(x);
  u = u + 0x7FFFu + ((u >> 16) & 1u);
  return u >> 16;
}
__device__ __forceinline__ float bf2f(unsigned int h) {
  return __uint_as_float(h << 16);
}

__device__ __forceinline__ void sysstore(float* p, float v) {
  __hip_atomic_store(p, v, __ATOMIC_RELAXED, __HIP_MEMORY_SCOPE_SYSTEM);
}
__device__ __forceinline__ int flagload(const int* p) {
  return __hip_atomic_load(p, __ATOMIC_RELAXED, __HIP_MEMORY_SCOPE_AGENT);
}
__device__ __forceinline__ void flagstore(int* p, int v) {
  __hip_atomic_store(p, v, __ATOMIC_RELAXED, __HIP_MEMORY_SCOPE_AGENT);
}

// cache-bypassing vector store (coherence-point data plane)
__device__ __forceinline__ void byp_store4(float* p, f32x4 v) {
  asm volatile("global_store_dwordx4 %0, %1, off sc0 sc1" :: "v"(p), "v"(v) : "memory");
}

// ---------------- pack GRU weights block-sliced: wpack[sl][c][kk], kk over [z|r|hx|hh] ----------------
__global__ void k_wt2(const float* __restrict__ zl, const float* __restrict__ rl,
                      const float* __restrict__ hl, float* __restrict__ wpack) {
  int idx = blockIdx.x*256 + threadIdx.x;       // 64*8*3072 = 1572864
  if (idx >= GRUB*8*3072) return;
  int kk = idx % 3072;
  int c  = (idx / 3072) & 7;
  int sl = idx / (3072*8);
  int ncol = sl*8 + c;
  float v;
  if (kk < 1024)      v = zl[ncol*1024 + kk];
  else if (kk < 2048) v = rl[ncol*1024 + (kk-1024)];
  else if (kk < 2560) v = hl[ncol*1024 + (kk-2048)];
  else                v = hl[ncol*1024 + 512 + (kk-2560)];
  wpack[idx] = v;
}

// ---------------- adaptive adjacency: softmax(relu(nv1@nv2), axis=1) ----------------
__global__ void k_adp(const float* __restrict__ nv1, const float* __restrict__ nv2,
                      float* __restrict__ adp) {
  int i = blockIdx.x;
  __shared__ float row[512];
  __shared__ float red[256];
  float v1[10];
  #pragma unroll
  for (int k=0;k<10;k++) v1[k] = nv1[i*10+k];
  for (int jj = threadIdx.x; jj < 512; jj += 256) {
    float s = 0.f;
    #pragma unroll
    for (int k=0;k<10;k++) s += v1[k]*nv2[k*Nn + jj];
    row[jj] = fmaxf(s, 0.f);
  }
  __syncthreads();
  float m = fmaxf(row[threadIdx.x], row[threadIdx.x+256]);
  red[threadIdx.x] = m; __syncthreads();
  for (int s=128; s>0; s>>=1) { if (threadIdx.x < s) red[threadIdx.x] = fmaxf(red[threadIdx.x], red[threadIdx.x+s]); __syncthreads(); }
  float mx = red[0]; __syncthreads();
  float e0 = expf(row[threadIdx.x]      - mx);
  float e1 = expf(row[threadIdx.x+256]  - mx);
  red[threadIdx.x] = e0 + e1; __syncthreads();
  for (int s=128; s>0; s>>=1) { if (threadIdx.x < s) red[threadIdx.x] += red[threadIdx.x+s]; __syncthreads(); }
  float inv = 1.f/red[0];
  adp[(size_t)i*Nn + threadIdx.x]       = e0*inv;
  adp[(size_t)i*Nn + threadIdx.x + 256] = e1*inv;
}

// ---------------- split 3 matrices to transposed bf16 hi/lo ----------------
__global__ void k_sprep(const float* __restrict__ S0, const float* __restrict__ S1,
                        const float* __restrict__ S2,
                        unsigned short* __restrict__ ShiT, unsigned short* __restrict__ SloT) {
  int idx = blockIdx.x*256 + threadIdx.x;
  if (idx >= 3*512*512) return;
  int s = idx >> 18;
  int rem = idx & 262143;
  int n = rem >> 9, k = rem & 511;
  const float* S = (s==0) ? S0 : (s==1) ? S1 : S2;
  float v = S[k*512 + n];
  unsigned int h = f2bf(v);
  float lo = v - bf2f(h);
  ShiT[idx] = (unsigned short)h;
  SloT[idx] = (unsigned short)f2bf(lo);
}

// ---------------- A2_s = A_s @ A_s (split-bf16 MFMA, fp32 out) ----------------
__launch_bounds__(256)
__global__ void k_aa(const float* __restrict__ sup0, const float* __restrict__ sup1,
                     const float* __restrict__ adp,
                     const unsigned short* __restrict__ ShiT6,
                     const unsigned short* __restrict__ SloT6,
                     float* __restrict__ A2) {
  __shared__ unsigned char smem[64*132*4];
  unsigned short* sXhi = (unsigned short*)smem;
  unsigned short* sXlo = sXhi + 2560;
  unsigned short* sShi = sXlo + 2560;
  unsigned short* sSlo = sShi + 5120;
  float* sY = (float*)smem;
#define MW 40
  const int tid  = threadIdx.x;
  const int bx   = blockIdx.x;
  const int s    = bx >> 5;
  const int r    = bx & 31;
  const int row0 = (r >> 2) * 64;
  const int n0   = (r & 3) * 128;
  const int lane = tid & 63, wv = tid >> 6;
  const int kb   = (lane >> 4)*8;
  const float* A = (s==0) ? sup0 : (s==1) ? sup1 : adp;
  const unsigned short* Shi = ShiT6 + (size_t)s*262144;
  const unsigned short* Slo = SloT6 + (size_t)s*262144;

  f32x4 acc[4][2];
  #pragma unroll
  for (int i=0;i<4;i++)
    #pragma unroll
    for (int j=0;j<2;j++) acc[i][j] = (f32x4){0.f,0.f,0.f,0.f};

  const int sm  = tid >> 2;
  const int skp = (tid & 3)*8;
  const size_t arow = (size_t)(row0 + sm)*512;
  const int sn  = tid >> 1;
  const int shp = (tid & 1)*16;

  for (int kc = 0; kc < 16; kc++) {
    const int k0 = kc*32;
    {
      float4 a0 = *reinterpret_cast<const float4*>(&A[arow + k0 + skp]);
      float4 a1 = *reinterpret_cast<const float4*>(&A[arow + k0 + skp + 4]);
      float v[8] = {a0.x,a0.y,a0.z,a0.w,a1.x,a1.y,a1.z,a1.w};
      unsigned int h[8], l[8];
      #pragma unroll
      for (int i=0;i<8;i++) { h[i] = f2bf(v[i]); l[i] = f2bf(v[i] - bf2f(h[i])); }
      uint4 H = { h[0]|(h[1]<<16), h[2]|(h[3]<<16), h[4]|(h[5]<<16), h[6]|(h[7]<<16) };
      uint4 L = { l[0]|(l[1]<<16), l[2]|(l[3]<<16), l[4]|(l[5]<<16), l[6]|(l[7]<<16) };
      *reinterpret_cast<uint4*>(&sXhi[sm*MW + skp]) = H;
      *reinterpret_cast<uint4*>(&sXlo[sm*MW + skp]) = L;
    }
    {
      const size_t srow = (size_t)(n0 + sn)*512 + k0 + shp;
      *reinterpret_cast<uint4*>(&sShi[sn*MW + shp])     = *reinterpret_cast<const uint4*>(&Shi[srow]);
      *reinterpret_cast<uint4*>(&sShi[sn*MW + shp + 8]) = *reinterpret_cast<const uint4*>(&Shi[srow + 8]);
      *reinterpret_cast<uint4*>(&sSlo[sn*MW + shp])     = *reinterpret_cast<const uint4*>(&Slo[srow]);
      *reinterpret_cast<uint4*>(&sSlo[sn*MW + shp + 8]) = *reinterpret_cast<const uint4*>(&Slo[srow + 8]);
    }
    __syncthreads();
    short8v bhi[2], blo[2];
    #pragma unroll
    for (int ct=0; ct<2; ct++) {
      int col = wv*32 + ct*16 + (lane & 15);
      bhi[ct] = *reinterpret_cast<const short8v*>(&sShi[col*MW + kb]);
      blo[ct] = *reinterpret_cast<const short8v*>(&sSlo[col*MW + kb]);
    }
    #pragma unroll
    for (int rt=0; rt<4; rt++) {
      int row = rt*16 + (lane & 15);
      short8v ahi = *reinterpret_cast<const short8v*>(&sXhi[row*MW + kb]);
      short8v alo = *reinterpret_cast<const short8v*>(&sXlo[row*MW + kb]);
      #pragma unroll
      for (int ct=0; ct<2; ct++) {
        acc[rt][ct] = __builtin_amdgcn_mfma_f32_16x16x32_bf16(ahi, bhi[ct], acc[rt][ct], 0, 0, 0);
        acc[rt][ct] = __builtin_amdgcn_mfma_f32_16x16x32_bf16(ahi, blo[ct], acc[rt][ct], 0, 0, 0);
        acc[rt][ct] = __builtin_amdgcn_mfma_f32_16x16x32_bf16(alo, bhi[ct], acc[rt][ct], 0, 0, 0);
      }
    }
    __syncthreads();
  }
  #pragma unroll
  for (int rt=0; rt<4; rt++) {
    #pragma unroll
    for (int ct=0; ct<2; ct++) {
      int col = wv*32 + ct*16 + (lane & 15);
      int rbase = rt*16 + (lane >> 4)*4;
      sY[(rbase+0)*132 + col] = acc[rt][ct].x;
      sY[(rbase+1)*132 + col] = acc[rt][ct].y;
      sY[(rbase+2)*132 + col] = acc[rt][ct].z;
      sY[(rbase+3)*132 + col] = acc[rt][ct].w;
    }
  }
  __syncthreads();
  for (int e = tid; e < 2048; e += 256) {
    int m = e >> 5, c4 = (e & 31)*4;
    float4 v = *reinterpret_cast<const float4*>(&sY[m*132 + c4]);
    *reinterpret_cast<float4*>(&A2[(size_t)s*262144 + (size_t)(row0 + m)*512 + n0 + c4]) = v;
  }
#undef MW
}

// ---------------- input transform ----------------
__global__ void k_intransform(const float* __restrict__ input, const float* __restrict__ skw,
                              const float* __restrict__ skb, float* __restrict__ x) {
  size_t idx = (size_t)blockIdx.x*256 + threadIdx.x;
  if (idx >= BTN) return;
  int n = idx & 511;
  size_t bt = idx >> 9;
  int b = (int)(bt / Tt), t = (int)(bt % Tt);
  size_t chs = (size_t)Tt*Nn;
  size_t base = (((size_t)b*7)*Tt + t)*Nn + n;
  float v0 = input[base + 0*chs];
  float v3 = input[base + 3*chs];
  float v5 = input[base + 5*chs];
  float v6 = input[base + 6*chs];
  float* xp = x + bt*Cc*Nn + n;
  #pragma unroll
  for (int c=0;c<32;c++)
    xp[(size_t)c*Nn] = skb[c] + skw[c*4+0]*v0 + skw[c*4+1]*v3 + skw[c*4+2]*v5 + skw[c*4+3]*v6;
}

// ---------------- fused filter/gate conv1x2 -> xg_q ; optional gout_q = W0@xg + bias ----------------
__launch_bounds__(256)
__global__ void k_fgconv(const float* __restrict__ x, const float* __restrict__ fw,
                         const float* __restrict__ fb, const float* __restrict__ gw,
                         const float* __restrict__ gb, const float* __restrict__ gcwl,
                         const float* __restrict__ gcb,
                         float* __restrict__ xg, float* __restrict__ gout,
                         int chunk, int wgout) {
  __shared__ float sfw[2048], sgw[2048], sw0[1024], sfb[32], sgb[32], sgcb[32];
  for (int l = threadIdx.x; l < 2048; l += 256) { sfw[l] = fw[l]; sgw[l] = gw[l]; }
  for (int l = threadIdx.x; l < 1024; l += 256) sw0[l] = gcwl[(l>>5)*224 + (l&31)];
  if (threadIdx.x < 32) {
    sfb[threadIdx.x] = fb[threadIdx.x];
    sgb[threadIdx.x] = gb[threadIdx.x];
    sgcb[threadIdx.x] = gcb[threadIdx.x];
  }
  __syncthreads();
  size_t idx = (size_t)blockIdx.x*256 + threadIdx.x;
  if (idx >= BTNc) return;
  int n = idx & 511;
  size_t btl = idx >> 9;
  int t = (int)(btl % Tt);
  size_t btg = (size_t)chunk*BTc + btl;
  const float* xp = x + btg*Cc*Nn + n;
  float xl[32], xr[32];
  #pragma unroll
  for (int c=0;c<32;c++) xr[c] = xp[(size_t)c*Nn];
  if (t == 0) {
    #pragma unroll
    for (int c=0;c<32;c++) xl[c] = 0.f;
  } else {
    const float* xq = xp - (size_t)Cc*Nn;
    #pragma unroll
    for (int c=0;c<32;c++) xl[c] = xq[(size_t)c*Nn];
  }
  float xgv[32];
  for (int c=0;c<32;c++) {
    float f = sfb[c], g = sgb[c];
    #pragma unroll
    for (int cp=0;cp<32;cp++) {
      f += xl[cp]*sfw[(c*32+cp)*2] + xr[cp]*sfw[(c*32+cp)*2+1];
      g += xl[cp]*sgw[(c*32+cp)*2] + xr[cp]*sgw[(c*32+cp)*2+1];
    }
    xgv[c] = tanhf(f) * sigm(g);
  }
  float* xgp = xg + btl*Cc*Nn + n;
  #pragma unroll
  for (int c=0;c<32;c++) xgp[(size_t)c*Nn] = xgv[c];
  if (wgout) {
    float* gp = gout + btl*Cc*Nn + n;
    for (int o=0;o<32;o++) {
      float s = sgcb[o];
      #pragma unroll
      for (int c=0;c<32;c++) s += sw0[o*32+c]*xgv[c];
      gp[(size_t)o*Nn] = s;
    }
  }
}

// ---------------- all-support GEMM v2: per-pair sW + VGPR prefetch pipeline ----------------
__launch_bounds__(256, 3)
__global__ void k_supall2(const float* __restrict__ X,
                          const unsigned short* __restrict__ ShiT6,
                          const unsigned short* __restrict__ SloT6,
                          const float* __restrict__ gcw,
                          float* __restrict__ gout) {
  __shared__ __align__(16) unsigned char smem[64*132*4];   // staging pool / sY
  __shared__ float sWp[1024];
  unsigned short* sXhi = (unsigned short*)smem;
  unsigned short* sXlo = sXhi + 2560;
  unsigned short* sShi = sXlo + 2560;
  unsigned short* sSlo = sShi + 5120;
  float* sY = (float*)smem;
#define MW 40
  const int tid  = threadIdx.x;
  const int bt2  = blockIdx.x >> 2;
  const int colg = blockIdx.x & 3;
  const int bt0  = bt2*2;
  const int n0   = colg*128;
  const int lane = tid & 63, wv = tid >> 6;
  const int kb   = (lane >> 4)*8;
  const int sm   = tid >> 2;
  const int skp  = (tid & 3)*8;
  const size_t xrow = ((size_t)(bt0 + (sm>>5))*Cc + (sm&31))*Nn;
  const int sn   = tid >> 1;
  const int shp  = (tid & 1)*16;
  const int tx = tid & 31, ty = tid >> 5;

  float og[2][4][4];
  #pragma unroll
  for (int bl=0;bl<2;bl++)
    #pragma unroll
    for (int i=0;i<4;i++)
      #pragma unroll
      for (int j=0;j<4;j++) og[bl][i][j] = 0.f;

  for (int p = 0; p < 6; p++) {
    const int s = p >> 1, j = p & 1;
    const int panel = j ? (3 + s) : s;
    const unsigned short* Shi = ShiT6 + (size_t)panel*262144;
    const unsigned short* Slo = SloT6 + (size_t)panel*262144;

    __syncthreads();   // previous pair's sY/sWp reads complete
    for (int l = tid; l < 1024; l += 256)
      sWp[l] = gcw[(l>>5)*224 + (p+1)*32 + (l&31)];
    // prologue: stage kc=0
    {
      float4 a0 = *reinterpret_cast<const float4*>(&X[xrow + skp]);
      float4 a1 = *reinterpret_cast<const float4*>(&X[xrow + skp + 4]);
      float v[8] = {a0.x,a0.y,a0.z,a0.w,a1.x,a1.y,a1.z,a1.w};
      unsigned int h[8], l[8];
      #pragma unroll
      for (int i=0;i<8;i++) { h[i] = f2bf(v[i]); l[i] = f2bf(v[i] - bf2f(h[i])); }
      uint4 H = { h[0]|(h[1]<<16), h[2]|(h[3]<<16), h[4]|(h[5]<<16), h[6]|(h[7]<<16) };
      uint4 L = { l[0]|(l[1]<<16), l[2]|(l[3]<<16), l[4]|(l[5]<<16), l[6]|(l[7]<<16) };
      *reinterpret_cast<uint4*>(&sXhi[sm*MW + skp]) = H;
      *reinterpret_cast<uint4*>(&sXlo[sm*MW + skp]) = L;
      const size_t srow = (size_t)(n0 + sn)*512 + shp;
      *reinterpret_cast<uint4*>(&sShi[sn*MW + shp])     = *reinterpret_cast<const uint4*>(&Shi[srow]);
      *reinterpret_cast<uint4*>(&sShi[sn*MW + shp + 8]) = *reinterpret_cast<const uint4*>(&Shi[srow + 8]);
      *reinterpret_cast<uint4*>(&sSlo[sn*MW + shp])     = *reinterpret_cast<const uint4*>(&Slo[srow]);
      *reinterpret_cast<uint4*>(&sSlo[sn*MW + shp + 8]) = *reinterpret_cast<const uint4*>(&Slo[srow + 8]);
    }
    __syncthreads();

    f32x4 acc[4][2];
    #pragma unroll
    for (int i=0;i<4;i++)
      #pragma unroll
      for (int jj=0;jj<2;jj++) acc[i][jj] = (f32x4){0.f,0.f,0.f,0.f};

    for (int kc = 0; kc < 16; kc++) {
      float4 pa0, pa1; uint4 ps0, ps1, ps2, ps3;
      if (kc < 15) {
        const int k1 = (kc+1)*32;
        pa0 = *reinterpret_cast<const float4*>(&X[xrow + k1 + skp]);
        pa1 = *reinterpret_cast<const float4*>(&X[xrow + k1 + skp + 4]);
        const size_t srow = (size_t)(n0 + sn)*512 + k1 + shp;
        ps0 = *reinterpret_cast<const uint4*>(&Shi[srow]);
        ps1 = *reinterpret_cast<const uint4*>(&Shi[srow + 8]);
        ps2 = *reinterpret_cast<const uint4*>(&Slo[srow]);
        ps3 = *reinterpret_cast<const uint4*>(&Slo[srow + 8]);
      }
      short8v bhi[2], blo[2];
      #pragma unroll
      for (int ct=0; ct<2; ct++) {
        int col = wv*32 + ct*16 + (lane & 15);
        bhi[ct] = *reinterpret_cast<const short8v*>(&sShi[col*MW + kb]);
        blo[ct] = *reinterpret_cast<const short8v*>(&sSlo[col*MW + kb]);
      }
      #pragma unroll
      for (int rt=0; rt<4; rt++) {
        int row = rt*16 + (lane & 15);
        short8v ahi = *reinterpret_cast<const short8v*>(&sXhi[row*MW + kb]);
        short8v alo = *reinterpret_cast<const short8v*>(&sXlo[row*MW + kb]);
        #pragma unroll
        for (int ct=0; ct<2; ct++) {
          acc[rt][ct] = __builtin_amdgcn_mfma_f32_16x16x32_bf16(ahi, bhi[ct], acc[rt][ct], 0, 0, 0);
          acc[rt][ct] = __builtin_amdgcn_mfma_f32_16x16x32_bf16(ahi, blo[ct], acc[rt][ct], 0, 0, 0);
          acc[rt][ct] = __builtin_amdgcn_mfma_f32_16x16x32_bf16(alo, bhi[ct], acc[rt][ct], 0, 0, 0);
        }
      }
      __syncthreads();
      if (kc < 15) {
        float v[8] = {pa0.x,pa0.y,pa0.z,pa0.w,pa1.x,pa1.y,pa1.z,pa1.w};
        unsigned int h[8], l[8];
        #pragma unroll
        for (int i=0;i<8;i++) { h[i] = f2bf(v[i]); l[i] = f2bf(v[i] - bf2f(h[i])); }
        uint4 H = { h[0]|(h[1]<<16), h[2]|(h[3]<<16), h[4]|(h[5]<<16), h[6]|(h[7]<<16) };
        uint4 L = { l[0]|(l[1]<<16), l[2]|(l[3]<<16), l[4]|(l[5]<<16), l[6]|(l[7]<<16) };
        *reinterpret_cast<uint4*>(&sXhi[sm*MW + skp]) = H;
        *reinterpret_cast<uint4*>(&sXlo[sm*MW + skp]) = L;
        *reinterpret_cast<uint4*>(&sShi[sn*MW + shp])     = ps0;
        *reinterpret_cast<uint4*>(&sShi[sn*MW + shp + 8]) = ps1;
        *reinterpret_cast<uint4*>(&sSlo[sn*MW + shp])     = ps2;
        *reinterpret_cast<uint4*>(&sSlo[sn*MW + shp + 8]) = ps3;
      }
      __syncthreads();
    }
    #pragma unroll
    for (int rt=0; rt<4; rt++) {
      #pragma unroll
      for (int ct=0; ct<2; ct++) {
        int col = wv*32 + ct*16 + (lane & 15);
        int rbase = rt*16 + (lane >> 4)*4;
        sY[(rbase+0)*132 + col] = acc[rt][ct].x;
        sY[(rbase+1)*132 + col] = acc[rt][ct].y;
        sY[(rbase+2)*132 + col] = acc[rt][ct].z;
        sY[(rbase+3)*132 + col] = acc[rt][ct].w;
      }
    }
    __syncthreads();
    for (int btl = 0; btl < 2; btl++) {
      #pragma unroll 8
      for (int c = 0; c < 32; c++) {
        float4 yv = *reinterpret_cast<const float4*>(&sY[(btl*32 + c)*132 + tx*4]);
        float w0 = sWp[((ty<<2)+0)*32 + c];
        float w1 = sWp[((ty<<2)+1)*32 + c];
        float w2 = sWp[((ty<<2)+2)*32 + c];
        float w3 = sWp[((ty<<2)+3)*32 + c];
        og[btl][0][0]+=w0*yv.x; og[btl][0][1]+=w0*yv.y; og[btl][0][2]+=w0*yv.z; og[btl][0][3]+=w0*yv.w;
        og[btl][1][0]+=w1*yv.x; og[btl][1][1]+=w1*yv.y; og[btl][1][2]+=w1*yv.z; og[btl][1][3]+=w1*yv.w;
        og[btl][2][0]+=w2*yv.x; og[btl][2][1]+=w2*yv.y; og[btl][2][2]+=w2*yv.z; og[btl][2][3]+=w2*yv.w;
        og[btl][3][0]+=w3*yv.x; og[btl][3][1]+=w3*yv.y; og[btl][3][2]+=w3*yv.z; og[btl][3][3]+=w3*yv.w;
      }
    }
  }
  for (int btl = 0; btl < 2; btl++) {
    float* gp = gout + (size_t)(bt0+btl)*Cc*Nn + n0 + (tx<<2);
    #pragma unroll
    for (int i=0;i<4;i++) {
      float4 cur = *reinterpret_cast<float4*>(gp + (size_t)((ty<<2)+i)*Nn);
      cur.x += og[btl][i][0]; cur.y += og[btl][i][1]; cur.z += og[btl][i][2]; cur.w += og[btl][i][3];
      *reinterpret_cast<float4*>(gp + (size_t)((ty<<2)+i)*Nn) = cur;
    }
  }
#undef MW
}

// ---------------- skip gather ----------------
__global__ void k_skipgather(const float* __restrict__ xg, const int* __restrict__ miss,
                             float* __restrict__ skipK, int chunk, int first) {
  int idx = blockIdx.x*256 + threadIdx.x;
  if (idx >= BPC*Kk*Tt) return;
  int t = idx % Tt;
  int k = (idx / Tt) % Kk;
  int bloc = idx / (Tt*Kk);
  int bg = chunk*BPC + bloc;
  int node = miss[bg*Kk + k];
  const float* xp = xg + (((size_t)bloc*Tt + t)*Cc)*Nn + node;
  float* sp = skipK + (((size_t)bg*Kk + k)*Cc)*Tt + t;
  #pragma unroll
  for (int c=0;c<32;c++) {
    float v = xp[(size_t)c*Nn];
    sp[(size_t)c*Tt] = first ? v : (sp[(size_t)c*Tt] + v);
  }
}

// ---------------- fused ingru + xfold ----------------
__global__ void k_ingruxf(const float* __restrict__ gout, const float* __restrict__ iw,
                          const float* __restrict__ ib2, float* __restrict__ Xs,
                          float* __restrict__ x, int chunk) {
  size_t idx = (size_t)blockIdx.x*256 + threadIdx.x;
  if (idx >= BTNc) return;
  int n = idx & 511;
  size_t btl = idx >> 9;
  int b = chunk*BPC + (int)(btl / Tt), t = (int)(btl % Tt);
  const float* gp = gout + btl*Cc*Nn + n;
  float* xp = x + ((size_t)chunk*BTc + btl)*Cc*Nn + n;
  float s = ib2[0];
  #pragma unroll
  for (int c=0;c<Cc;c++) {
    float g = gp[(size_t)c*Nn];
    s += iw[c]*g;
    xp[(size_t)c*Nn] += g;
  }
  Xs[((size_t)t*Bb + b)*Nn + n] = s;
}

// ---------------- GRU v7 (round-10 proven): wave-decoupled, per-batch flags ----------------
__launch_bounds__(512, 1)
__global__ void k_gru7(const float* __restrict__ Xs, const float* __restrict__ input,
                       const float* __restrict__ wpack,
                       const float* __restrict__ zb, const float* __restrict__ rb,
                       const float* __restrict__ hb,
                       float* __restrict__ xh_g, float* __restrict__ rh_g,
                       float* __restrict__ outs, int* __restrict__ flags) {
  __shared__ float wl[8*3072];
  const int tid = threadIdx.x;
  const int sl  = blockIdx.x;
  const int n0  = sl*8;
  const int b   = tid >> 6;
  const int q   = tid & 63;

  {
    const float4* src = reinterpret_cast<const float4*>(wpack + (size_t)sl*24576);
    float4* dst = reinterpret_cast<float4*>(wl);
    #pragma unroll 4
    for (int i = tid; i < 6144; i += 512) dst[i] = src[i];
  }
  if (q < 8) {
    int nn = n0 + q;
    float Xi = Xs[(size_t)b*Nn + nn];
    float Mi = input[(((size_t)b*7+1)*Tt + 0)*Nn + nn];
    sysstore(xh_g + b*1024 + 512 + nn, 0.f);
    sysstore(xh_g + b*1024 + nn, sigm(Xi*Mi));
  }
  __syncthreads();
  asm volatile("s_waitcnt vmcnt(0)" ::: "memory");
  if (q == 0) flagstore(flags + (b*64 + sl)*32, 1);

  const int* pollfl = flags + (b*64 + q)*32;
  int* myfl = flags + (b*64 + sl)*32;

  float zbv[8], rbv[8], hbv[8];
  #pragma unroll
  for (int c=0;c<8;c++) { zbv[c]=zb[n0+c]; rbv[c]=rb[n0+c]; hbv[c]=hb[n0+c]; }

  const float* bp = xh_g + b*1024;
  const float* rp = rh_g + b*512;

  for (int t = 0; t < Tt; t++) {
    float4 xiA, xiB, miA, miB;
    {
      int tp = (t+1 < Tt) ? (t+1) : t;
      const float* xsp = Xs + ((size_t)tp*Bb + b)*Nn + n0;
      const float* mip = input + (((size_t)b*7+1)*Tt + tp)*Nn + n0;
      xiA = *reinterpret_cast<const float4*>(xsp);
      xiB = *reinterpret_cast<const float4*>(xsp + 4);
      miA = *reinterpret_cast<const float4*>(mip);
      miB = *reinterpret_cast<const float4*>(mip + 4);
    }
    {
      int tgt = 1 + 2*t;
      while (!__all(flagload(pollfl) >= tgt)) __builtin_amdgcn_s_sleep(1);
    }
    f32x2 xv[8]; f32x4 h0v, h1v;
    asm volatile(
      "global_load_dwordx2 %0, %10, off sc0 sc1\n\t"
      "global_load_dwordx2 %1, %11, off sc0 sc1\n\t"
      "global_load_dwordx2 %2, %12, off sc0 sc1\n\t"
      "global_load_dwordx2 %3, %13, off sc0 sc1\n\t"
      "global_load_dwordx2 %4, %14, off sc0 sc1\n\t"
      "global_load_dwordx2 %5, %15, off sc0 sc1\n\t"
      "global_load_dwordx2 %6, %16, off sc0 sc1\n\t"
      "global_load_dwordx2 %7, %17, off sc0 sc1\n\t"
      "global_load_dwordx4 %8, %18, off sc0 sc1\n\t"
      "global_load_dwordx4 %9, %19, off sc0 sc1\n\t"
      "s_waitcnt vmcnt(0)"
      : "=&v"(xv[0]), "=&v"(xv[1]), "=&v"(xv[2]), "=&v"(xv[3]),
        "=&v"(xv[4]), "=&v"(xv[5]), "=&v"(xv[6]), "=&v"(xv[7]),
        "=&v"(h0v), "=&v"(h1v)
      : "v"(bp + 0*128 + q*2), "v"(bp + 1*128 + q*2), "v"(bp + 2*128 + q*2), "v"(bp + 3*128 + q*2),
        "v"(bp + 4*128 + q*2), "v"(bp + 5*128 + q*2), "v"(bp + 6*128 + q*2), "v"(bp + 7*128 + q*2),
        "v"(bp + 512 + n0), "v"(bp + 512 + n0 + 4)
      : "memory");
    float hold[8] = {h0v.x, h0v.y, h0v.z, h0v.w, h1v.x, h1v.y, h1v.z, h1v.w};
    float az[8], ar[8], ax[8];
    #pragma unroll
    for (int c=0;c<8;c++) { az[c]=0.f; ar[c]=0.f; ax[c]=0.f; }
    #pragma unroll
    for (int i = 0; i < 8; i++) {
      int k = i*128 + q*2;
      #pragma unroll
      for (int c = 0; c < 8; c++) {
        float2 wz = *reinterpret_cast<const float2*>(wl + c*3072 + k);
        float2 wr = *reinterpret_cast<const float2*>(wl + c*3072 + 1024 + k);
        az[c] += xv[i].x*wz.x + xv[i].y*wz.y;
        ar[c] += xv[i].x*wr.x + xv[i].y*wr.y;
      }
    }
    #pragma unroll
    for (int i = 0; i < 4; i++) {
      int k = i*128 + q*2;
      #pragma unroll
      for (int c = 0; c < 8; c++) {
        float2 wx = *reinterpret_cast<const float2*>(wl + c*3072 + 2048 + k);
        ax[c] += xv[i].x*wx.x + xv[i].y*wx.y;
      }
    }
    #pragma unroll
    for (int d = 1; d < 64; d <<= 1) {
      #pragma unroll
      for (int c = 0; c < 8; c++) {
        az[c] += __shfl_xor(az[c], d);
        ar[c] += __shfl_xor(ar[c], d);
        ax[c] += __shfl_xor(ax[c], d);
      }
    }
    float zs[8], rh[8];
    #pragma unroll
    for (int c = 0; c < 8; c++) {
      zs[c] = sigm(az[c] + zbv[c]);
      float r = sigm(ar[c] + rbv[c]);
      rh[c] = r * hold[c];
    }
    if (q == 0) {
      f32x4 r0 = {rh[0],rh[1],rh[2],rh[3]};
      f32x4 r1 = {rh[4],rh[5],rh[6],rh[7]};
      byp_store4(rh_g + b*512 + n0,     r0);
      byp_store4(rh_g + b*512 + n0 + 4, r1);
      asm volatile("s_waitcnt vmcnt(0)" ::: "memory");
      flagstore(myfl, 2 + 2*t);
    }
    {
      int tgt = 2 + 2*t;
      while (!__all(flagload(pollfl) >= tgt)) __builtin_amdgcn_s_sleep(1);
    }
    f32x2 rv[4];
    asm volatile(
      "global_load_dwordx2 %0, %4, off sc0 sc1\n\t"
      "global_load_dwordx2 %1, %5, off sc0 sc1\n\t"
      "global_load_dwordx2 %2, %6, off sc0 sc1\n\t"
      "global_load_dwordx2 %3, %7, off sc0 sc1\n\t"
      "s_waitcnt vmcnt(0)"
      : "=&v"(rv[0]), "=&v"(rv[1]), "=&v"(rv[2]), "=&v"(rv[3])
      : "v"(rp + 0*128 + q*2), "v"(rp + 1*128 + q*2), "v"(rp + 2*128 + q*2), "v"(rp + 3*128 + q*2)
      : "memory");
    float ah[8];
    #pragma unroll
    for (int c=0;c<8;c++) ah[c]=0.f;
    #pragma unroll
    for (int i = 0; i < 4; i++) {
      int k = i*128 + q*2;
      #pragma unroll
      for (int c = 0; c < 8; c++) {
        float2 wh = *reinterpret_cast<const float2*>(wl + c*3072 + 2560 + k);
        ah[c] += rv[i].x*wh.x + rv[i].y*wh.y;
      }
    }
    #pragma unroll
    for (int d = 1; d < 64; d <<= 1) {
      #pragma unroll
      for (int c = 0; c < 8; c++) ah[c] += __shfl_xor(ah[c], d);
    }
    float hn[8];
    #pragma unroll
    for (int c = 0; c < 8; c++) {
      float ht = tanhf(ax[c] + ah[c] + hbv[c]);
      hn[c] = (1.f - zs[c])*hold[c] + zs[c]*ht;
    }
    if (q == 0) {
      f32x4 h0 = {hn[0],hn[1],hn[2],hn[3]};
      f32x4 h1 = {hn[4],hn[5],hn[6],hn[7]};
      *reinterpret_cast<f32x4*>(&outs[((size_t)t*Bb + b)*Nn + n0])     = h0;
      *reinterpret_cast<f32x4*>(&outs[((size_t)t*Bb + b)*Nn + n0 + 4]) = h1;
      byp_store4(xh_g + b*1024 + 512 + n0,     h0);
      byp_store4(xh_g + b*1024 + 512 + n0 + 4, h1);
      if (t+1 < Tt) {
        f32x4 x0, x1;
        x0.x = sigm(xiA.x*miA.x + hn[0]*(1.f - miA.x));
        x0.y = sigm(xiA.y*miA.y + hn[1]*(1.f - miA.y));
        x0.z = sigm(xiA.z*miA.z + hn[2]*(1.f - miA.z));
        x0.w = sigm(xiA.w*miA.w + hn[3]*(1.f - miA.w));
        x1.x = sigm(xiB.x*miB.x + hn[4]*(1.f - miB.x));
        x1.y = sigm(xiB.y*miB.y + hn[5]*(1.f - miB.y));
        x1.z = sigm(xiB.z*miB.z + hn[6]*(1.f - miB.z));
        x1.w = sigm(xiB.w*miB.w + hn[7]*(1.f - miB.w));
        byp_store4(xh_g + b*1024 + n0,     x0);
        byp_store4(xh_g + b*1024 + n0 + 4, x1);
      }
      asm volatile("s_waitcnt vmcnt(0)" ::: "memory");
      flagstore(myfl, 3 + 2*t);
    }
  }
}

// ---------------- x += outs*rw + rb (after GRU) ----------------
__global__ void k_xre(float* __restrict__ x, const float* __restrict__ outs,
                      const float* __restrict__ rw, const float* __restrict__ rb2) {
  size_t idx = (size_t)blockIdx.x*256 + threadIdx.x;
  if (idx >= BTCN) return;
  int n = idx & 511;
  int c = (int)((idx >> 9) & 31);
  size_t bt = idx >> 14;
  int b = (int)(bt / Tt), t = (int)(bt % Tt);
  float o = outs[((size_t)t*Bb + b)*Nn + n];
  x[idx] += o*rw[c] + rb2[c];
}

// ---------------- head: relu(skipK) -> end1 relu -> end2 ----------------
__launch_bounds__(256)
__global__ void k_head(const float* __restrict__ skipK,
                       const float* __restrict__ e1w, const float* __restrict__ e1b,
                       const float* __restrict__ e2w, const float* __restrict__ e2b,
                       float* __restrict__ out) {
  __shared__ float sw[2048], sb[64], s2[64];
  for (int l = threadIdx.x; l < 2048; l += 256) sw[l] = e1w[l];
  if (threadIdx.x < 64) { sb[threadIdx.x] = e1b[threadIdx.x]; s2[threadIdx.x] = e2w[threadIdx.x]; }
  __syncthreads();
  int idx = blockIdx.x*256 + threadIdx.x;
  if (idx >= Bb*Kk*Tt) return;
  int t = idx % Tt;
  int k = (idx / Tt) % Kk;
  int b = idx / (Tt*Kk);
  const float* sp = skipK + (((size_t)b*Kk + k)*Cc)*Tt + t;
  float in[32];
  #pragma unroll
  for (int c=0;c<32;c++) in[c] = fmaxf(sp[(size_t)c*Tt], 0.f);
  float acc = e2b[0];
  for (int o=0;o<64;o++) {
    float s = sb[o];
    #pragma unroll
    for (int c=0;c<32;c++) s += sw[o*32+c]*in[c];
    acc += s2[o]*fmaxf(s, 0.f);
  }
  out[idx] = acc;
}

extern "C" void kernel_launch(void* const* d_in, const int* in_sizes, int n_in,
                              void* d_out, int out_size, void* d_ws, size_t ws_size,
                              hipStream_t stream) {
  const float* input = (const float*)d_in[0];
  const int*   miss  = (const int*)  d_in[1];
  const float* sup0  = (const float*)d_in[2];
  const float* sup1  = (const float*)d_in[3];
  const float* nv1   = (const float*)d_in[4];
  const float* nv2   = (const float*)d_in[5];
  const float* skw   = (const float*)d_in[6];
  const float* skb   = (const float*)d_in[7];
  const float* fw    = (const float*)d_in[8];
  const float* fb    = (const float*)d_in[9];
  const float* gw    = (const float*)d_in[10];
  const float* gb    = (const float*)d_in[11];
  const float* gcw   = (const float*)d_in[12];
  const float* gcb   = (const float*)d_in[13];
  const float* iw    = (const float*)d_in[14];
  const float* ib2   = (const float*)d_in[15];
  const float* rw    = (const float*)d_in[16];
  const float* rb2   = (const float*)d_in[17];
  const float* zl    = (const float*)d_in[18];
  const float* zb    = (const float*)d_in[19];
  const float* rl    = (const float*)d_in[20];
  const float* rb    = (const float*)d_in[21];
  const float* hl    = (const float*)d_in[22];
  const float* hb    = (const float*)d_in[23];
  const float* e1w   = (const float*)d_in[24];
  const float* e1b   = (const float*)d_in[25];
  const float* e2w   = (const float*)d_in[26];
  const float* e2b   = (const float*)d_in[27];
  float* out = (float*)d_out;

  float* p     = (float*)d_ws;
  float* x     = p; p += BTCN;
  float* xg    = p; p += BTCNc;
  float* gout  = p; p += BTCNc;
  float* skipK = p; p += (size_t)Bb*Kk*Cc*Tt;
  float* adp   = p; p += (size_t)Nn*Nn;
  float* A2    = p; p += (size_t)3*Nn*Nn;
  float* wpack = p; p += (size_t)GRUB*8*3072;
  unsigned short* ShiT6 = (unsigned short*)p; p += (size_t)(6*512*512)/2;
  unsigned short* SloT6 = (unsigned short*)p; p += (size_t)(6*512*512)/2;
  float* Xs    = p; p += (size_t)Tt*Bb*Nn;
  float* outs  = p; p += (size_t)Tt*Bb*Nn;
  float* xh_g  = p; p += Bb*1024;
  float* rh_g  = p; p += Bb*512;
  int*   flags = (int*)p; p += (size_t)Bb*GRUB*32;

  k_wt2<<<(GRUB*8*3072 + 255)/256, 256, 0, stream>>>(zl, rl, hl, wpack);
  k_adp<<<Nn, 256, 0, stream>>>(nv1, nv2, adp);
  k_sprep<<<(3*512*512 + 255)/256, 256, 0, stream>>>(sup0, sup1, adp, ShiT6, SloT6);
  k_aa<<<96, 256, 0, stream>>>(sup0, sup1, adp, ShiT6, SloT6, A2);
  k_sprep<<<(3*512*512 + 255)/256, 256, 0, stream>>>(A2, A2 + 262144, A2 + 524288,
                                                     ShiT6 + 3*262144, SloT6 + 3*262144);
  k_intransform<<<(int)((BTN + 255)/256), 256, 0, stream>>>(input, skw, skb, x);

  for (int layer = 0; layer < Ll; layer++) {
    const int last = (layer == Ll - 1);
    for (int chunk = 0; chunk < NCH; chunk++) {
      k_fgconv<<<(int)((BTNc + 255)/256), 256, 0, stream>>>(
          x, fw + layer*2048, fb + layer*32, gw + layer*2048, gb + layer*32,
          gcw + layer*32*224, gcb + layer*32,
          xg, gout, chunk, last ? 0 : 1);
      if (!last) {
        k_supall2<<<dim3((BTc/2)*4), 256, 0, stream>>>(
            xg, ShiT6, SloT6, gcw + layer*32*224, gout);
      }
      k_skipgather<<<(BPC*Kk*Tt + 255)/256, 256, 0, stream>>>(xg, miss, skipK, chunk, layer == 0 ? 1 : 0);
      if (!last) {
        k_ingruxf<<<(int)((BTNc + 255)/256), 256, 0, stream>>>(gout, iw, ib2, Xs, x, chunk);
      }
    }
    if (!last) {
      (void)hipMemsetAsync(flags, 0, (size_t)Bb*GRUB*32*sizeof(int), stream);
      k_gru7<<<dim3(GRUB), dim3(512), 0, stream>>>(
          Xs, input, wpack, zb, rb, hb, xh_g, rh_g, outs, flags);
      k_xre<<<(int)((BTCN + 255)/256), 256, 0, stream>>>(x, outs, rw, rb2);
    }
  }
  k_head<<<(Bb*Kk*Tt + 255)/256, 256, 0, stream>>>(skipK, e1w, e1b, e2w, e2b, out);
}

// Round 16
// 10825.901 us; speedup vs baseline: 1.6514x; 1.0159x over previous
//
#include <hip/hip_runtime.h>
#include <math.h>

#define Bb 8
#define Tt 168
#define Nn 512
#define Cc 32
#define Ll 4
#define Kk 50
#define NCH 4
#define BPC 2                     // batches per chunk (chunk boundary = t==0, no cross-chunk reads)
#define BTc (BPC*Tt)              // 336
#define BTNc ((size_t)BTc*Nn)
#define BTCNc ((size_t)BTc*Cc*Nn)
#define BT (Bb*Tt)
#define BTN ((size_t)Bb*Tt*Nn)
#define BTCN ((size_t)Bb*Tt*Cc*Nn)
#define GRUB 64                   // GRU blocks: each owns 8 output cols, all batches

typedef __attribute__((ext_vector_type(8))) short short8v;
typedef __attribute__((ext_vector_type(4))) float f32x4;
typedef __attribute__((ext_vector_type(2))) float f32x2;

__device__ __forceinline__ float sigm(float v) { return 1.0f/(1.0f + expf(-v)); }

__device__ __forceinline__ unsigned int f2bf(float x) {   // RNE, returns bits in low 16
  unsigned int u = __float_as_uint(x);
  u = u + 0x7FFFu + ((u >> 16) & 1u);
  return u >> 16;
}
__device__ __forceinline__ float bf2f(unsigned int h) {
  return __uint_as_float(h << 16);
}

__device__ __forceinline__ void sysstore(float* p, float v) {
  __hip_atomic_store(p, v, __ATOMIC_RELAXED, __HIP_MEMORY_SCOPE_SYSTEM);
}
__device__ __forceinline__ int flagload(const int* p) {
  return __hip_atomic_load(p, __ATOMIC_RELAXED, __HIP_MEMORY_SCOPE_AGENT);
}
__device__ __forceinline__ void flagstore(int* p, int v) {
  __hip_atomic_store(p, v, __ATOMIC_RELAXED, __HIP_MEMORY_SCOPE_AGENT);
}

// cache-bypassing vector store (coherence-point data plane)
__device__ __forceinline__ void byp_store4(float* p, f32x4 v) {
  asm volatile("global_store_dwordx4 %0, %1, off sc0 sc1" :: "v"(p), "v"(v) : "memory");
}

// ---------------- pack GRU weights block-sliced: wpack[sl][c][kk], kk over [z|r|hx|hh] ----------------
__global__ void k_wt2(const float* __restrict__ zl, const float* __restrict__ rl,
                      const float* __restrict__ hl, float* __restrict__ wpack) {
  int idx = blockIdx.x*256 + threadIdx.x;       // 64*8*3072 = 1572864
  if (idx >= GRUB*8*3072) return;
  int kk = idx % 3072;
  int c  = (idx / 3072) & 7;
  int sl = idx / (3072*8);
  int ncol = sl*8 + c;
  float v;
  if (kk < 1024)      v = zl[ncol*1024 + kk];
  else if (kk < 2048) v = rl[ncol*1024 + (kk-1024)];
  else if (kk < 2560) v = hl[ncol*1024 + (kk-2048)];
  else                v = hl[ncol*1024 + 512 + (kk-2560)];
  wpack[idx] = v;
}

// ---------------- adaptive adjacency: softmax(relu(nv1@nv2), axis=1) ----------------
__global__ void k_adp(const float* __restrict__ nv1, const float* __restrict__ nv2,
                      float* __restrict__ adp) {
  int i = blockIdx.x;
  __shared__ float row[512];
  __shared__ float red[256];
  float v1[10];
  #pragma unroll
  for (int k=0;k<10;k++) v1[k] = nv1[i*10+k];
  for (int jj = threadIdx.x; jj < 512; jj += 256) {
    float s = 0.f;
    #pragma unroll
    for (int k=0;k<10;k++) s += v1[k]*nv2[k*Nn + jj];
    row[jj] = fmaxf(s, 0.f);
  }
  __syncthreads();
  float m = fmaxf(row[threadIdx.x], row[threadIdx.x+256]);
  red[threadIdx.x] = m; __syncthreads();
  for (int s=128; s>0; s>>=1) { if (threadIdx.x < s) red[threadIdx.x] = fmaxf(red[threadIdx.x], red[threadIdx.x+s]); __syncthreads(); }
  float mx = red[0]; __syncthreads();
  float e0 = expf(row[threadIdx.x]      - mx);
  float e1 = expf(row[threadIdx.x+256]  - mx);
  red[threadIdx.x] = e0 + e1; __syncthreads();
  for (int s=128; s>0; s>>=1) { if (threadIdx.x < s) red[threadIdx.x] += red[threadIdx.x+s]; __syncthreads(); }
  float inv = 1.f/red[0];
  adp[(size_t)i*Nn + threadIdx.x]       = e0*inv;
  adp[(size_t)i*Nn + threadIdx.x + 256] = e1*inv;
}

// ---------------- split 3 matrices to transposed bf16 hi/lo ----------------
__global__ void k_sprep(const float* __restrict__ S0, const float* __restrict__ S1,
                        const float* __restrict__ S2,
                        unsigned short* __restrict__ ShiT, unsigned short* __restrict__ SloT) {
  int idx = blockIdx.x*256 + threadIdx.x;
  if (idx >= 3*512*512) return;
  int s = idx >> 18;
  int rem = idx & 262143;
  int n = rem >> 9, k = rem & 511;
  const float* S = (s==0) ? S0 : (s==1) ? S1 : S2;
  float v = S[k*512 + n];
  unsigned int h = f2bf(v);
  float lo = v - bf2f(h);
  ShiT[idx] = (unsigned short)h;
  SloT[idx] = (unsigned short)f2bf(lo);
}

// ---------------- A2_s = A_s @ A_s (split-bf16 MFMA, fp32 out) ----------------
__launch_bounds__(256)
__global__ void k_aa(const float* __restrict__ sup0, const float* __restrict__ sup1,
                     const float* __restrict__ adp,
                     const unsigned short* __restrict__ ShiT6,
                     const unsigned short* __restrict__ SloT6,
                     float* __restrict__ A2) {
  __shared__ unsigned char smem[64*132*4];
  unsigned short* sXhi = (unsigned short*)smem;
  unsigned short* sXlo = sXhi + 2560;
  unsigned short* sShi = sXlo + 2560;
  unsigned short* sSlo = sShi + 5120;
  float* sY = (float*)smem;
#define MW 40
  const int tid  = threadIdx.x;
  const int bx   = blockIdx.x;
  const int s    = bx >> 5;
  const int r    = bx & 31;
  const int row0 = (r >> 2) * 64;
  const int n0   = (r & 3) * 128;
  const int lane = tid & 63, wv = tid >> 6;
  const int kb   = (lane >> 4)*8;
  const float* A = (s==0) ? sup0 : (s==1) ? sup1 : adp;
  const unsigned short* Shi = ShiT6 + (size_t)s*262144;
  const unsigned short* Slo = SloT6 + (size_t)s*262144;

  f32x4 acc[4][2];
  #pragma unroll
  for (int i=0;i<4;i++)
    #pragma unroll
    for (int j=0;j<2;j++) acc[i][j] = (f32x4){0.f,0.f,0.f,0.f};

  const int sm  = tid >> 2;
  const int skp = (tid & 3)*8;
  const size_t arow = (size_t)(row0 + sm)*512;
  const int sn  = tid >> 1;
  const int shp = (tid & 1)*16;

  for (int kc = 0; kc < 16; kc++) {
    const int k0 = kc*32;
    {
      float4 a0 = *reinterpret_cast<const float4*>(&A[arow + k0 + skp]);
      float4 a1 = *reinterpret_cast<const float4*>(&A[arow + k0 + skp + 4]);
      float v[8] = {a0.x,a0.y,a0.z,a0.w,a1.x,a1.y,a1.z,a1.w};
      unsigned int h[8], l[8];
      #pragma unroll
      for (int i=0;i<8;i++) { h[i] = f2bf(v[i]); l[i] = f2bf(v[i] - bf2f(h[i])); }
      uint4 H = { h[0]|(h[1]<<16), h[2]|(h[3]<<16), h[4]|(h[5]<<16), h[6]|(h[7]<<16) };
      uint4 L = { l[0]|(l[1]<<16), l[2]|(l[3]<<16), l[4]|(l[5]<<16), l[6]|(l[7]<<16) };
      *reinterpret_cast<uint4*>(&sXhi[sm*MW + skp]) = H;
      *reinterpret_cast<uint4*>(&sXlo[sm*MW + skp]) = L;
    }
    {
      const size_t srow = (size_t)(n0 + sn)*512 + k0 + shp;
      *reinterpret_cast<uint4*>(&sShi[sn*MW + shp])     = *reinterpret_cast<const uint4*>(&Shi[srow]);
      *reinterpret_cast<uint4*>(&sShi[sn*MW + shp + 8]) = *reinterpret_cast<const uint4*>(&Shi[srow + 8]);
      *reinterpret_cast<uint4*>(&sSlo[sn*MW + shp])     = *reinterpret_cast<const uint4*>(&Slo[srow]);
      *reinterpret_cast<uint4*>(&sSlo[sn*MW + shp + 8]) = *reinterpret_cast<const uint4*>(&Slo[srow + 8]);
    }
    __syncthreads();
    short8v bhi[2], blo[2];
    #pragma unroll
    for (int ct=0; ct<2; ct++) {
      int col = wv*32 + ct*16 + (lane & 15);
      bhi[ct] = *reinterpret_cast<const short8v*>(&sShi[col*MW + kb]);
      blo[ct] = *reinterpret_cast<const short8v*>(&sSlo[col*MW + kb]);
    }
    #pragma unroll
    for (int rt=0; rt<4; rt++) {
      int row = rt*16 + (lane & 15);
      short8v ahi = *reinterpret_cast<const short8v*>(&sXhi[row*MW + kb]);
      short8v alo = *reinterpret_cast<const short8v*>(&sXlo[row*MW + kb]);
      #pragma unroll
      for (int ct=0; ct<2; ct++) {
        acc[rt][ct] = __builtin_amdgcn_mfma_f32_16x16x32_bf16(ahi, bhi[ct], acc[rt][ct], 0, 0, 0);
        acc[rt][ct] = __builtin_amdgcn_mfma_f32_16x16x32_bf16(ahi, blo[ct], acc[rt][ct], 0, 0, 0);
        acc[rt][ct] = __builtin_amdgcn_mfma_f32_16x16x32_bf16(alo, bhi[ct], acc[rt][ct], 0, 0, 0);
      }
    }
    __syncthreads();
  }
  #pragma unroll
  for (int rt=0; rt<4; rt++) {
    #pragma unroll
    for (int ct=0; ct<2; ct++) {
      int col = wv*32 + ct*16 + (lane & 15);
      int rbase = rt*16 + (lane >> 4)*4;
      sY[(rbase+0)*132 + col] = acc[rt][ct].x;
      sY[(rbase+1)*132 + col] = acc[rt][ct].y;
      sY[(rbase+2)*132 + col] = acc[rt][ct].z;
      sY[(rbase+3)*132 + col] = acc[rt][ct].w;
    }
  }
  __syncthreads();
  for (int e = tid; e < 2048; e += 256) {
    int m = e >> 5, c4 = (e & 31)*4;
    float4 v = *reinterpret_cast<const float4*>(&sY[m*132 + c4]);
    *reinterpret_cast<float4*>(&A2[(size_t)s*262144 + (size_t)(row0 + m)*512 + n0 + c4]) = v;
  }
#undef MW
}

// ---------------- input transform ----------------
__global__ void k_intransform(const float* __restrict__ input, const float* __restrict__ skw,
                              const float* __restrict__ skb, float* __restrict__ x) {
  size_t idx = (size_t)blockIdx.x*256 + threadIdx.x;
  if (idx >= BTN) return;
  int n = idx & 511;
  size_t bt = idx >> 9;
  int b = (int)(bt / Tt), t = (int)(bt % Tt);
  size_t chs = (size_t)Tt*Nn;
  size_t base = (((size_t)b*7)*Tt + t)*Nn + n;
  float v0 = input[base + 0*chs];
  float v3 = input[base + 3*chs];
  float v5 = input[base + 5*chs];
  float v6 = input[base + 6*chs];
  float* xp = x + bt*Cc*Nn + n;
  #pragma unroll
  for (int c=0;c<32;c++)
    xp[(size_t)c*Nn] = skb[c] + skw[c*4+0]*v0 + skw[c*4+1]*v3 + skw[c*4+2]*v5 + skw[c*4+3]*v6;
}

// ---------------- fgconv2: conv1x2 -> xg/gout (optional) + FUSED skip scatter ----------------
// One block = 256 consecutive n of one (chunk-local bt) => single batch bg; miss list in LDS;
// matching threads scatter xgv into skipK (RMW for layer>0). Last layer: no xg/gout writes.
__launch_bounds__(256)
__global__ void k_fgconv2(const float* __restrict__ x, const float* __restrict__ fw,
                          const float* __restrict__ fb, const float* __restrict__ gw,
                          const float* __restrict__ gb, const float* __restrict__ gcwl,
                          const float* __restrict__ gcb,
                          const int* __restrict__ miss, float* __restrict__ skipK,
                          float* __restrict__ xg, float* __restrict__ gout,
                          int chunk, int wxg, int first) {
  __shared__ float sfw[2048], sgw[2048], sw0[1024], sfb[32], sgb[32], sgcb[32];
  __shared__ int smiss[Kk];
  size_t idx = (size_t)blockIdx.x*256 + threadIdx.x;
  int n = idx & 511;
  size_t btl = idx >> 9;
  int t = (int)(btl % Tt);
  int bg = chunk*BPC + (int)(btl / Tt);
  for (int l = threadIdx.x; l < 2048; l += 256) { sfw[l] = fw[l]; sgw[l] = gw[l]; }
  for (int l = threadIdx.x; l < 1024; l += 256) sw0[l] = gcwl[(l>>5)*224 + (l&31)];
  if (threadIdx.x < 32) {
    sfb[threadIdx.x] = fb[threadIdx.x];
    sgb[threadIdx.x] = gb[threadIdx.x];
    sgcb[threadIdx.x] = gcb[threadIdx.x];
  }
  if (threadIdx.x < Kk) smiss[threadIdx.x] = miss[bg*Kk + threadIdx.x];
  __syncthreads();
  const float* xp = x + ((size_t)chunk*BTc + btl)*Cc*Nn + n;
  float xl[32], xr[32];
  #pragma unroll
  for (int c=0;c<32;c++) xr[c] = xp[(size_t)c*Nn];
  if (t == 0) {
    #pragma unroll
    for (int c=0;c<32;c++) xl[c] = 0.f;
  } else {
    const float* xq = xp - (size_t)Cc*Nn;
    #pragma unroll
    for (int c=0;c<32;c++) xl[c] = xq[(size_t)c*Nn];
  }
  float xgv[32];
  for (int c=0;c<32;c++) {
    float f = sfb[c], g = sgb[c];
    #pragma unroll
    for (int cp=0;cp<32;cp++) {
      f += xl[cp]*sfw[(c*32+cp)*2] + xr[cp]*sfw[(c*32+cp)*2+1];
      g += xl[cp]*sgw[(c*32+cp)*2] + xr[cp]*sgw[(c*32+cp)*2+1];
    }
    xgv[c] = tanhf(f) * sigm(g);
  }
  if (wxg) {
    float* xgp = xg + btl*Cc*Nn + n;
    #pragma unroll
    for (int c=0;c<32;c++) xgp[(size_t)c*Nn] = xgv[c];
    float* gp = gout + btl*Cc*Nn + n;
    for (int o=0;o<32;o++) {
      float s = sgcb[o];
      #pragma unroll
      for (int c=0;c<32;c++) s += sw0[o*32+c]*xgv[c];
      gp[(size_t)o*Nn] = s;
    }
  }
  // fused skip scatter
  for (int k = 0; k < Kk; k++) {
    if (smiss[k] == n) {
      float* sp = skipK + (((size_t)bg*Kk + k)*Cc)*Tt + t;
      if (first) {
        #pragma unroll
        for (int c=0;c<32;c++) sp[(size_t)c*Tt] = xgv[c];
      } else {
        #pragma unroll
        for (int c=0;c<32;c++) sp[(size_t)c*Tt] += xgv[c];
      }
    }
  }
}

// ---------------- supall3: 6-pair support GEMM + FUSED ingru/xfold epilogue ----------------
// After accumulating og: cur = gout(fgconv W0 part) + og; x += cur; Xs = ib + sum_c iw[c]*cur.
// gout is never written back (no downstream reader).
__launch_bounds__(256, 3)
__global__ void k_supall3(const float* __restrict__ X,
                          const unsigned short* __restrict__ ShiT6,
                          const unsigned short* __restrict__ SloT6,
                          const float* __restrict__ gcw,
                          const float* __restrict__ gout,
                          const float* __restrict__ iw, const float* __restrict__ ib2,
                          float* __restrict__ x, float* __restrict__ Xs, int chunk) {
  __shared__ __align__(16) unsigned char smem[64*132*4];   // staging pool / sY / sRed
  __shared__ float sWp[1024];
  __shared__ float siw[32];
  unsigned short* sXhi = (unsigned short*)smem;
  unsigned short* sXlo = sXhi + 2560;
  unsigned short* sShi = sXlo + 2560;
  unsigned short* sSlo = sShi + 5120;
  float* sY = (float*)smem;
#define MW 40
  const int tid  = threadIdx.x;
  const int bt2  = blockIdx.x >> 2;
  const int colg = blockIdx.x & 3;
  const int bt0  = bt2*2;
  const int n0   = colg*128;
  const int lane = tid & 63, wv = tid >> 6;
  const int kb   = (lane >> 4)*8;
  const int sm   = tid >> 2;
  const int skp  = (tid & 3)*8;
  const size_t xrow = ((size_t)(bt0 + (sm>>5))*Cc + (sm&31))*Nn;
  const int sn   = tid >> 1;
  const int shp  = (tid & 1)*16;
  const int tx = tid & 31, ty = tid >> 5;

  if (tid < 32) siw[tid] = iw[tid];

  float og[2][4][4];
  #pragma unroll
  for (int bl=0;bl<2;bl++)
    #pragma unroll
    for (int i=0;i<4;i++)
      #pragma unroll
      for (int j=0;j<4;j++) og[bl][i][j] = 0.f;

  for (int p = 0; p < 6; p++) {
    const int s = p >> 1, j = p & 1;
    const int panel = j ? (3 + s) : s;
    const unsigned short* Shi = ShiT6 + (size_t)panel*262144;
    const unsigned short* Slo = SloT6 + (size_t)panel*262144;

    __syncthreads();
    for (int l = tid; l < 1024; l += 256)
      sWp[l] = gcw[(l>>5)*224 + (p+1)*32 + (l&31)];
    {
      float4 a0 = *reinterpret_cast<const float4*>(&X[xrow + skp]);
      float4 a1 = *reinterpret_cast<const float4*>(&X[xrow + skp + 4]);
      float v[8] = {a0.x,a0.y,a0.z,a0.w,a1.x,a1.y,a1.z,a1.w};
      unsigned int h[8], l[8];
      #pragma unroll
      for (int i=0;i<8;i++) { h[i] = f2bf(v[i]); l[i] = f2bf(v[i] - bf2f(h[i])); }
      uint4 H = { h[0]|(h[1]<<16), h[2]|(h[3]<<16), h[4]|(h[5]<<16), h[6]|(h[7]<<16) };
      uint4 L = { l[0]|(l[1]<<16), l[2]|(l[3]<<16), l[4]|(l[5]<<16), l[6]|(l[7]<<16) };
      *reinterpret_cast<uint4*>(&sXhi[sm*MW + skp]) = H;
      *reinterpret_cast<uint4*>(&sXlo[sm*MW + skp]) = L;
      const size_t srow = (size_t)(n0 + sn)*512 + shp;
      *reinterpret_cast<uint4*>(&sShi[sn*MW + shp])     = *reinterpret_cast<const uint4*>(&Shi[srow]);
      *reinterpret_cast<uint4*>(&sShi[sn*MW + shp + 8]) = *reinterpret_cast<const uint4*>(&Shi[srow + 8]);
      *reinterpret_cast<uint4*>(&sSlo[sn*MW + shp])     = *reinterpret_cast<const uint4*>(&Slo[srow]);
      *reinterpret_cast<uint4*>(&sSlo[sn*MW + shp + 8]) = *reinterpret_cast<const uint4*>(&Slo[srow + 8]);
    }
    __syncthreads();

    f32x4 acc[4][2];
    #pragma unroll
    for (int i=0;i<4;i++)
      #pragma unroll
      for (int jj=0;jj<2;jj++) acc[i][jj] = (f32x4){0.f,0.f,0.f,0.f};

    for (int kc = 0; kc < 16; kc++) {
      float4 pa0, pa1; uint4 ps0, ps1, ps2, ps3;
      if (kc < 15) {
        const int k1 = (kc+1)*32;
        pa0 = *reinterpret_cast<const float4*>(&X[xrow + k1 + skp]);
        pa1 = *reinterpret_cast<const float4*>(&X[xrow + k1 + skp + 4]);
        const size_t srow = (size_t)(n0 + sn)*512 + k1 + shp;
        ps0 = *reinterpret_cast<const uint4*>(&Shi[srow]);
        ps1 = *reinterpret_cast<const uint4*>(&Shi[srow + 8]);
        ps2 = *reinterpret_cast<const uint4*>(&Slo[srow]);
        ps3 = *reinterpret_cast<const uint4*>(&Slo[srow + 8]);
      }
      short8v bhi[2], blo[2];
      #pragma unroll
      for (int ct=0; ct<2; ct++) {
        int col = wv*32 + ct*16 + (lane & 15);
        bhi[ct] = *reinterpret_cast<const short8v*>(&sShi[col*MW + kb]);
        blo[ct] = *reinterpret_cast<const short8v*>(&sSlo[col*MW + kb]);
      }
      #pragma unroll
      for (int rt=0; rt<4; rt++) {
        int row = rt*16 + (lane & 15);
        short8v ahi = *reinterpret_cast<const short8v*>(&sXhi[row*MW + kb]);
        short8v alo = *reinterpret_cast<const short8v*>(&sXlo[row*MW + kb]);
        #pragma unroll
        for (int ct=0; ct<2; ct++) {
          acc[rt][ct] = __builtin_amdgcn_mfma_f32_16x16x32_bf16(ahi, bhi[ct], acc[rt][ct], 0, 0, 0);
          acc[rt][ct] = __builtin_amdgcn_mfma_f32_16x16x32_bf16(ahi, blo[ct], acc[rt][ct], 0, 0, 0);
          acc[rt][ct] = __builtin_amdgcn_mfma_f32_16x16x32_bf16(alo, bhi[ct], acc[rt][ct], 0, 0, 0);
        }
      }
      __syncthreads();
      if (kc < 15) {
        float v[8] = {pa0.x,pa0.y,pa0.z,pa0.w,pa1.x,pa1.y,pa1.z,pa1.w};
        unsigned int h[8], l[8];
        #pragma unroll
        for (int i=0;i<8;i++) { h[i] = f2bf(v[i]); l[i] = f2bf(v[i] - bf2f(h[i])); }
        uint4 H = { h[0]|(h[1]<<16), h[2]|(h[3]<<16), h[4]|(h[5]<<16), h[6]|(h[7]<<16) };
        uint4 L = { l[0]|(l[1]<<16), l[2]|(l[3]<<16), l[4]|(l[5]<<16), l[6]|(l[7]<<16) };
        *reinterpret_cast<uint4*>(&sXhi[sm*MW + skp]) = H;
        *reinterpret_cast<uint4*>(&sXlo[sm*MW + skp]) = L;
        *reinterpret_cast<uint4*>(&sShi[sn*MW + shp])     = ps0;
        *reinterpret_cast<uint4*>(&sShi[sn*MW + shp + 8]) = ps1;
        *reinterpret_cast<uint4*>(&sSlo[sn*MW + shp])     = ps2;
        *reinterpret_cast<uint4*>(&sSlo[sn*MW + shp + 8]) = ps3;
      }
      __syncthreads();
    }
    #pragma unroll
    for (int rt=0; rt<4; rt++) {
      #pragma unroll
      for (int ct=0; ct<2; ct++) {
        int col = wv*32 + ct*16 + (lane & 15);
        int rbase = rt*16 + (lane >> 4)*4;
        sY[(rbase+0)*132 + col] = acc[rt][ct].x;
        sY[(rbase+1)*132 + col] = acc[rt][ct].y;
        sY[(rbase+2)*132 + col] = acc[rt][ct].z;
        sY[(rbase+3)*132 + col] = acc[rt][ct].w;
      }
    }
    __syncthreads();
    for (int btl = 0; btl < 2; btl++) {
      #pragma unroll 8
      for (int c = 0; c < 32; c++) {
        float4 yv = *reinterpret_cast<const float4*>(&sY[(btl*32 + c)*132 + tx*4]);
        float w0 = sWp[((ty<<2)+0)*32 + c];
        float w1 = sWp[((ty<<2)+1)*32 + c];
        float w2 = sWp[((ty<<2)+2)*32 + c];
        float w3 = sWp[((ty<<2)+3)*32 + c];
        og[btl][0][0]+=w0*yv.x; og[btl][0][1]+=w0*yv.y; og[btl][0][2]+=w0*yv.z; og[btl][0][3]+=w0*yv.w;
        og[btl][1][0]+=w1*yv.x; og[btl][1][1]+=w1*yv.y; og[btl][1][2]+=w1*yv.z; og[btl][1][3]+=w1*yv.w;
        og[btl][2][0]+=w2*yv.x; og[btl][2][1]+=w2*yv.y; og[btl][2][2]+=w2*yv.z; og[btl][2][3]+=w2*yv.w;
        og[btl][3][0]+=w3*yv.x; og[btl][3][1]+=w3*yv.y; og[btl][3][2]+=w3*yv.z; og[btl][3][3]+=w3*yv.w;
      }
    }
  }
  // ---- fused epilogue: cur = gout + og; x += cur; Xs = ib + sum_c iw[c]*cur ----
  __syncthreads();                  // sY reads done; reuse pool as sRed[8][128]
  float* sRed = (float*)smem;
  const float ib = ib2[0];
  for (int btl = 0; btl < 2; btl++) {
    const int btg = bt0 + btl;      // chunk-local bt
    const float* gp = gout + (size_t)btg*Cc*Nn + n0 + (tx<<2);
    float* xp = x + ((size_t)chunk*BTc + btg)*Cc*Nn + n0 + (tx<<2);
    float part[4] = {0.f, 0.f, 0.f, 0.f};
    #pragma unroll
    for (int i=0;i<4;i++) {
      float4 cur = *reinterpret_cast<const float4*>(gp + (size_t)((ty<<2)+i)*Nn);
      cur.x += og[btl][i][0]; cur.y += og[btl][i][1]; cur.z += og[btl][i][2]; cur.w += og[btl][i][3];
      float4 xv = *reinterpret_cast<const float4*>(xp + (size_t)((ty<<2)+i)*Nn);
      xv.x += cur.x; xv.y += cur.y; xv.z += cur.z; xv.w += cur.w;
      *reinterpret_cast<float4*>(xp + (size_t)((ty<<2)+i)*Nn) = xv;
      float w = siw[(ty<<2)+i];
      part[0] += w*cur.x; part[1] += w*cur.y; part[2] += w*cur.z; part[3] += w*cur.w;
    }
    *reinterpret_cast<float4*>(&sRed[ty*128 + (tx<<2)]) =
        make_float4(part[0], part[1], part[2], part[3]);
    __syncthreads();
    if (tid < 128) {
      float s = ib;
      #pragma unroll
      for (int g = 0; g < 8; g++) s += sRed[g*128 + tid];
      int b = chunk*BPC + btg/Tt, t = btg % Tt;
      Xs[((size_t)t*Bb + b)*Nn + n0 + tid] = s;
    }
    __syncthreads();
  }
#undef MW
}

// ---------------- GRU v7 (round-10 proven): wave-decoupled, per-batch flags ----------------
__launch_bounds__(512, 1)
__global__ void k_gru7(const float* __restrict__ Xs, const float* __restrict__ input,
                       const float* __restrict__ wpack,
                       const float* __restrict__ zb, const float* __restrict__ rb,
                       const float* __restrict__ hb,
                       float* __restrict__ xh_g, float* __restrict__ rh_g,
                       float* __restrict__ outs, int* __restrict__ flags) {
  __shared__ float wl[8*3072];
  const int tid = threadIdx.x;
  const int sl  = blockIdx.x;
  const int n0  = sl*8;
  const int b   = tid >> 6;
  const int q   = tid & 63;

  {
    const float4* src = reinterpret_cast<const float4*>(wpack + (size_t)sl*24576);
    float4* dst = reinterpret_cast<float4*>(wl);
    #pragma unroll 4
    for (int i = tid; i < 6144; i += 512) dst[i] = src[i];
  }
  if (q < 8) {
    int nn = n0 + q;
    float Xi = Xs[(size_t)b*Nn + nn];
    float Mi = input[(((size_t)b*7+1)*Tt + 0)*Nn + nn];
    sysstore(xh_g + b*1024 + 512 + nn, 0.f);
    sysstore(xh_g + b*1024 + nn, sigm(Xi*Mi));
  }
  __syncthreads();
  asm volatile("s_waitcnt vmcnt(0)" ::: "memory");
  if (q == 0) flagstore(flags + (b*64 + sl)*32, 1);

  const int* pollfl = flags + (b*64 + q)*32;
  int* myfl = flags + (b*64 + sl)*32;

  float zbv[8], rbv[8], hbv[8];
  #pragma unroll
  for (int c=0;c<8;c++) { zbv[c]=zb[n0+c]; rbv[c]=rb[n0+c]; hbv[c]=hb[n0+c]; }

  const float* bp = xh_g + b*1024;
  const float* rp = rh_g + b*512;

  for (int t = 0; t < Tt; t++) {
    float4 xiA, xiB, miA, miB;
    {
      int tp = (t+1 < Tt) ? (t+1) : t;
      const float* xsp = Xs + ((size_t)tp*Bb + b)*Nn + n0;
      const float* mip = input + (((size_t)b*7+1)*Tt + tp)*Nn + n0;
      xiA = *reinterpret_cast<const float4*>(xsp);
      xiB = *reinterpret_cast<const float4*>(xsp + 4);
      miA = *reinterpret_cast<const float4*>(mip);
      miB = *reinterpret_cast<const float4*>(mip + 4);
    }
    {
      int tgt = 1 + 2*t;
      while (!__all(flagload(pollfl) >= tgt)) __builtin_amdgcn_s_sleep(1);
    }
    f32x2 xv[8]; f32x4 h0v, h1v;
    asm volatile(
      "global_load_dwordx2 %0, %10, off sc0 sc1\n\t"
      "global_load_dwordx2 %1, %11, off sc0 sc1\n\t"
      "global_load_dwordx2 %2, %12, off sc0 sc1\n\t"
      "global_load_dwordx2 %3, %13, off sc0 sc1\n\t"
      "global_load_dwordx2 %4, %14, off sc0 sc1\n\t"
      "global_load_dwordx2 %5, %15, off sc0 sc1\n\t"
      "global_load_dwordx2 %6, %16, off sc0 sc1\n\t"
      "global_load_dwordx2 %7, %17, off sc0 sc1\n\t"
      "global_load_dwordx4 %8, %18, off sc0 sc1\n\t"
      "global_load_dwordx4 %9, %19, off sc0 sc1\n\t"
      "s_waitcnt vmcnt(0)"
      : "=&v"(xv[0]), "=&v"(xv[1]), "=&v"(xv[2]), "=&v"(xv[3]),
        "=&v"(xv[4]), "=&v"(xv[5]), "=&v"(xv[6]), "=&v"(xv[7]),
        "=&v"(h0v), "=&v"(h1v)
      : "v"(bp + 0*128 + q*2), "v"(bp + 1*128 + q*2), "v"(bp + 2*128 + q*2), "v"(bp + 3*128 + q*2),
        "v"(bp + 4*128 + q*2), "v"(bp + 5*128 + q*2), "v"(bp + 6*128 + q*2), "v"(bp + 7*128 + q*2),
        "v"(bp + 512 + n0), "v"(bp + 512 + n0 + 4)
      : "memory");
    float hold[8] = {h0v.x, h0v.y, h0v.z, h0v.w, h1v.x, h1v.y, h1v.z, h1v.w};
    float az[8], ar[8], ax[8];
    #pragma unroll
    for (int c=0;c<8;c++) { az[c]=0.f; ar[c]=0.f; ax[c]=0.f; }
    #pragma unroll
    for (int i = 0; i < 8; i++) {
      int k = i*128 + q*2;
      #pragma unroll
      for (int c = 0; c < 8; c++) {
        float2 wz = *reinterpret_cast<const float2*>(wl + c*3072 + k);
        float2 wr = *reinterpret_cast<const float2*>(wl + c*3072 + 1024 + k);
        az[c] += xv[i].x*wz.x + xv[i].y*wz.y;
        ar[c] += xv[i].x*wr.x + xv[i].y*wr.y;
      }
    }
    #pragma unroll
    for (int i = 0; i < 4; i++) {
      int k = i*128 + q*2;
      #pragma unroll
      for (int c = 0; c < 8; c++) {
        float2 wx = *reinterpret_cast<const float2*>(wl + c*3072 + 2048 + k);
        ax[c] += xv[i].x*wx.x + xv[i].y*wx.y;
      }
    }
    #pragma unroll
    for (int d = 1; d < 64; d <<= 1) {
      #pragma unroll
      for (int c = 0; c < 8; c++) {
        az[c] += __shfl_xor(az[c], d);
        ar[c] += __shfl_xor(ar[c], d);
        ax[c] += __shfl_xor(ax[c], d);
      }
    }
    float zs[8], rh[8];
    #pragma unroll
    for (int c = 0; c < 8; c++) {
      zs[c] = sigm(az[c] + zbv[c]);
      float r = sigm(ar[c] + rbv[c]);
      rh[c] = r * hold[c];
    }
    if (q == 0) {
      f32x4 r0 = {rh[0],rh[1],rh[2],rh[3]};
      f32x4 r1 = {rh[4],rh[5],rh[6],rh[7]};
      byp_store4(rh_g + b*512 + n0,     r0);
      byp_store4(rh_g + b*512 + n0 + 4, r1);
      asm volatile("s_waitcnt vmcnt(0)" ::: "memory");
      flagstore(myfl, 2 + 2*t);
    }
    {
      int tgt = 2 + 2*t;
      while (!__all(flagload(pollfl) >= tgt)) __builtin_amdgcn_s_sleep(1);
    }
    f32x2 rv[4];
    asm volatile(
      "global_load_dwordx2 %0, %4, off sc0 sc1\n\t"
      "global_load_dwordx2 %1, %5, off sc0 sc1\n\t"
      "global_load_dwordx2 %2, %6, off sc0 sc1\n\t"
      "global_load_dwordx2 %3, %7, off sc0 sc1\n\t"
      "s_waitcnt vmcnt(0)"
      : "=&v"(rv[0]), "=&v"(rv[1]), "=&v"(rv[2]), "=&v"(rv[3])
      : "v"(rp + 0*128 + q*2), "v"(rp + 1*128 + q*2), "v"(rp + 2*128 + q*2), "v"(rp + 3*128 + q*2)
      : "memory");
    float ah[8];
    #pragma unroll
    for (int c=0;c<8;c++) ah[c]=0.f;
    #pragma unroll
    for (int i = 0; i < 4; i++) {
      int k = i*128 + q*2;
      #pragma unroll
      for (int c = 0; c < 8; c++) {
        float2 wh = *reinterpret_cast<const float2*>(wl + c*3072 + 2560 + k);
        ah[c] += rv[i].x*wh.x + rv[i].y*wh.y;
      }
    }
    #pragma unroll
    for (int d = 1; d < 64; d <<= 1) {
      #pragma unroll
      for (int c = 0; c < 8; c++) ah[c] += __shfl_xor(ah[c], d);
    }
    float hn[8];
    #pragma unroll
    for (int c = 0; c < 8; c++) {
      float ht = tanhf(ax[c] + ah[c] + hbv[c]);
      hn[c] = (1.f - zs[c])*hold[c] + zs[c]*ht;
    }
    if (q == 0) {
      f32x4 h0 = {hn[0],hn[1],hn[2],hn[3]};
      f32x4 h1 = {hn[4],hn[5],hn[6],hn[7]};
      *reinterpret_cast<f32x4*>(&outs[((size_t)t*Bb + b)*Nn + n0])     = h0;
      *reinterpret_cast<f32x4*>(&outs[((size_t)t*Bb + b)*Nn + n0 + 4]) = h1;
      byp_store4(xh_g + b*1024 + 512 + n0,     h0);
      byp_store4(xh_g + b*1024 + 512 + n0 + 4, h1);
      if (t+1 < Tt) {
        f32x4 x0, x1;
        x0.x = sigm(xiA.x*miA.x + hn[0]*(1.f - miA.x));
        x0.y = sigm(xiA.y*miA.y + hn[1]*(1.f - miA.y));
        x0.z = sigm(xiA.z*miA.z + hn[2]*(1.f - miA.z));
        x0.w = sigm(xiA.w*miA.w + hn[3]*(1.f - miA.w));
        x1.x = sigm(xiB.x*miB.x + hn[4]*(1.f - miB.x));
        x1.y = sigm(xiB.y*miB.y + hn[5]*(1.f - miB.y));
        x1.z = sigm(xiB.z*miB.z + hn[6]*(1.f - miB.z));
        x1.w = sigm(xiB.w*miB.w + hn[7]*(1.f - miB.w));
        byp_store4(xh_g + b*1024 + n0,     x0);
        byp_store4(xh_g + b*1024 + n0 + 4, x1);
      }
      asm volatile("s_waitcnt vmcnt(0)" ::: "memory");
      flagstore(myfl, 3 + 2*t);
    }
  }
}

// ---------------- x += outs*rw + rb (after GRU) ----------------
__global__ void k_xre(float* __restrict__ x, const float* __restrict__ outs,
                      const float* __restrict__ rw, const float* __restrict__ rb2) {
  size_t idx = (size_t)blockIdx.x*256 + threadIdx.x;
  if (idx >= BTCN) return;
  int n = idx & 511;
  int c = (int)((idx >> 9) & 31);
  size_t bt = idx >> 14;
  int b = (int)(bt / Tt), t = (int)(bt % Tt);
  float o = outs[((size_t)t*Bb + b)*Nn + n];
  x[idx] += o*rw[c] + rb2[c];
}

// ---------------- head: relu(skipK) -> end1 relu -> end2 ----------------
__launch_bounds__(256)
__global__ void k_head(const float* __restrict__ skipK,
                       const float* __restrict__ e1w, const float* __restrict__ e1b,
                       const float* __restrict__ e2w, const float* __restrict__ e2b,
                       float* __restrict__ out) {
  __shared__ float sw[2048], sb[64], s2[64];
  for (int l = threadIdx.x; l < 2048; l += 256) sw[l] = e1w[l];
  if (threadIdx.x < 64) { sb[threadIdx.x] = e1b[threadIdx.x]; s2[threadIdx.x] = e2w[threadIdx.x]; }
  __syncthreads();
  int idx = blockIdx.x*256 + threadIdx.x;
  if (idx >= Bb*Kk*Tt) return;
  int t = idx % Tt;
  int k = (idx / Tt) % Kk;
  int b = idx / (Tt*Kk);
  const float* sp = skipK + (((size_t)b*Kk + k)*Cc)*Tt + t;
  float in[32];
  #pragma unroll
  for (int c=0;c<32;c++) in[c] = fmaxf(sp[(size_t)c*Tt], 0.f);
  float acc = e2b[0];
  for (int o=0;o<64;o++) {
    float s = sb[o];
    #pragma unroll
    for (int c=0;c<32;c++) s += sw[o*32+c]*in[c];
    acc += s2[o]*fmaxf(s, 0.f);
  }
  out[idx] = acc;
}

extern "C" void kernel_launch(void* const* d_in, const int* in_sizes, int n_in,
                              void* d_out, int out_size, void* d_ws, size_t ws_size,
                              hipStream_t stream) {
  const float* input = (const float*)d_in[0];
  const int*   miss  = (const int*)  d_in[1];
  const float* sup0  = (const float*)d_in[2];
  const float* sup1  = (const float*)d_in[3];
  const float* nv1   = (const float*)d_in[4];
  const float* nv2   = (const float*)d_in[5];
  const float* skw   = (const float*)d_in[6];
  const float* skb   = (const float*)d_in[7];
  const float* fw    = (const float*)d_in[8];
  const float* fb    = (const float*)d_in[9];
  const float* gw    = (const float*)d_in[10];
  const float* gb    = (const float*)d_in[11];
  const float* gcw   = (const float*)d_in[12];
  const float* gcb   = (const float*)d_in[13];
  const float* iw    = (const float*)d_in[14];
  const float* ib2   = (const float*)d_in[15];
  const float* rw    = (const float*)d_in[16];
  const float* rb2   = (const float*)d_in[17];
  const float* zl    = (const float*)d_in[18];
  const float* zb    = (const float*)d_in[19];
  const float* rl    = (const float*)d_in[20];
  const float* rb    = (const float*)d_in[21];
  const float* hl    = (const float*)d_in[22];
  const float* hb    = (const float*)d_in[23];
  const float* e1w   = (const float*)d_in[24];
  const float* e1b   = (const float*)d_in[25];
  const float* e2w   = (const float*)d_in[26];
  const float* e2b   = (const float*)d_in[27];
  float* out = (float*)d_out;

  float* p     = (float*)d_ws;
  float* x     = p; p += BTCN;
  float* xg    = p; p += BTCNc;
  float* gout  = p; p += BTCNc;
  float* skipK = p; p += (size_t)Bb*Kk*Cc*Tt;
  float* adp   = p; p += (size_t)Nn*Nn;
  float* A2    = p; p += (size_t)3*Nn*Nn;
  float* wpack = p; p += (size_t)GRUB*8*3072;
  unsigned short* ShiT6 = (unsigned short*)p; p += (size_t)(6*512*512)/2;
  unsigned short* SloT6 = (unsigned short*)p; p += (size_t)(6*512*512)/2;
  float* Xs    = p; p += (size_t)Tt*Bb*Nn;
  float* outs  = p; p += (size_t)Tt*Bb*Nn;
  float* xh_g  = p; p += Bb*1024;
  float* rh_g  = p; p += Bb*512;
  int*   flags = (int*)p; p += (size_t)Bb*GRUB*32;

  k_wt2<<<(GRUB*8*3072 + 255)/256, 256, 0, stream>>>(zl, rl, hl, wpack);
  k_adp<<<Nn, 256, 0, stream>>>(nv1, nv2, adp);
  k_sprep<<<(3*512*512 + 255)/256, 256, 0, stream>>>(sup0, sup1, adp, ShiT6, SloT6);
  k_aa<<<96, 256, 0, stream>>>(sup0, sup1, adp, ShiT6, SloT6, A2);
  k_sprep<<<(3*512*512 + 255)/256, 256, 0, stream>>>(A2, A2 + 262144, A2 + 524288,
                                                     ShiT6 + 3*262144, SloT6 + 3*262144);
  k_intransform<<<(int)((BTN + 255)/256), 256, 0, stream>>>(input, skw, skb, x);

  for (int layer = 0; layer < Ll; layer++) {
    const int last = (layer == Ll - 1);
    for (int chunk = 0; chunk < NCH; chunk++) {
      k_fgconv2<<<(int)((BTNc + 255)/256), 256, 0, stream>>>(
          x, fw + layer*2048, fb + layer*32, gw + layer*2048, gb + layer*32,
          gcw + layer*32*224, gcb + layer*32,
          miss, skipK, xg, gout, chunk, last ? 0 : 1, layer == 0 ? 1 : 0);
      if (!last) {
        k_supall3<<<dim3((BTc/2)*4), 256, 0, stream>>>(
            xg, ShiT6, SloT6, gcw + layer*32*224, gout, iw, ib2, x, Xs, chunk);
      }
    }
    if (!last) {
      (void)hipMemsetAsync(flags, 0, (size_t)Bb*GRUB*32*sizeof(int), stream);
      k_gru7<<<dim3(GRUB), dim3(512), 0, stream>>>(
          Xs, input, wpack, zb, rb, hb, xh_g, rh_g, outs, flags);
      k_xre<<<(int)((BTCN + 255)/256), 256, 0, stream>>>(x, outs, rw, rb2);
    }
  }
  k_head<<<(Bb*Kk*Tt + 255)/256, 256, 0, stream>>>(skipK, e1w, e1b, e2w, e2b, out);
}